// Round 1
// 1123.661 us; speedup vs baseline: 1.0295x; 1.0295x over previous
//
#include <hip/hip_runtime.h>
#include <hip/hip_bf16.h>
#include <math.h>

#define DM    1024
#define NH1   16
#define HDIM1 64
#define NH2   8
#define HDIM2 128
#define NE    8
#define CAPE  320
#define BATCH 8
#define SEQ   1024
#define NTOK  (BATCH*SEQ)        /* 8192 */
#define OUTN  ((long)NTOK*DM)    /* 8388608 */
#define ECB   ((long)BATCH*CAPE*DM)  /* 2,621,440 elems per expert */

typedef short bf16x8 __attribute__((ext_vector_type(8)));
typedef float f32x4  __attribute__((ext_vector_type(4)));

__device__ __forceinline__ unsigned short f2bf(float f) {
    __hip_bfloat16 h = __float2bfloat16(f);
    return *reinterpret_cast<unsigned short*>(&h);
}
__device__ __forceinline__ float bf2f(unsigned short u) {
    unsigned int x = ((unsigned int)u) << 16;
    return __builtin_bit_cast(float, x);
}

__device__ __forceinline__ void async16(const void* g, void* lds) {
    __builtin_amdgcn_global_load_lds(
        (const __attribute__((address_space(1))) unsigned int*)g,
        (__attribute__((address_space(3))) unsigned int*)lds, 16, 0, 0);
}

// ---------------- shared GEMM core: 128x128 tile, BK=32, 4 waves --------
// acc[i][j] accumulates C-tile (wr,wc wave grid). A[M,K], Bt[N,K] bf16.
__device__ __forceinline__ void gemm_core(
    const unsigned short* __restrict__ A, const unsigned short* __restrict__ Bt,
    int m0, int n0, int K, short* ldsA, short* ldsB, f32x4 (&acc)[4][4])
{
    const int t    = threadIdx.x;
    const int lane = t & 63, w = t >> 6;
    const int wr = w >> 1, wc = w & 1;
    const int lq = lane >> 4, lm = lane & 15;
    const int srow = w*16 + (lane >> 2);
    const int skc  = (lane & 3) * 8;
    for (int kb = 0; kb < K; kb += 32) {
        #pragma unroll
        for (int p = 0; p < 2; ++p) {
            async16(A  + (size_t)(m0 + srow + p*64)*K + kb + skc,
                    &ldsA[(w*16 + p*64)*32]);
            async16(Bt + (size_t)(n0 + srow + p*64)*K + kb + skc,
                    &ldsB[(w*16 + p*64)*32]);
        }
        __syncthreads();
        bf16x8 aF[4], bF[4];
        #pragma unroll
        for (int i = 0; i < 4; ++i)
            aF[i] = *(const bf16x8*)&ldsA[(wr*64 + i*16 + lm)*32 + lq*8];
        #pragma unroll
        for (int j = 0; j < 4; ++j)
            bF[j] = *(const bf16x8*)&ldsB[(wc*64 + j*16 + lm)*32 + lq*8];
        #pragma unroll
        for (int i = 0; i < 4; ++i)
            #pragma unroll
            for (int j = 0; j < 4; ++j)
                acc[i][j] = __builtin_amdgcn_mfma_f32_16x16x32_bf16(aF[i], bF[j], acc[i][j], 0, 0, 0);
        __syncthreads();
    }
}

// ---------------- plain GEMM (fp32 out, bias) — used for Wo projection ----
__global__ __launch_bounds__(256) void gemm_bt_f32(
    const unsigned short* __restrict__ A, const unsigned short* __restrict__ Bt,
    const float* __restrict__ bias, float* __restrict__ C, int N, int K)
{
    __shared__ short ldsA[128*32];
    __shared__ short ldsB[128*32];
    const int lane = threadIdx.x & 63, w = threadIdx.x >> 6;
    const int wr = w >> 1, wc = w & 1;
    const int lq = lane >> 4, lm = lane & 15;
    const int m0 = blockIdx.y * 128, n0 = blockIdx.x * 128;
    f32x4 acc[4][4];
    #pragma unroll
    for (int i = 0; i < 4; ++i)
        #pragma unroll
        for (int j = 0; j < 4; ++j) acc[i][j] = (f32x4){0.f,0.f,0.f,0.f};
    gemm_core(A, Bt, m0, n0, K, ldsA, ldsB, acc);
    #pragma unroll
    for (int j = 0; j < 4; ++j) {
        const int gcol = n0 + wc*64 + j*16 + lm;
        const float badd = bias ? bias[gcol] : 0.f;
        #pragma unroll
        for (int i = 0; i < 4; ++i) {
            const int grow = m0 + wr*64 + i*16 + lq*4;
            #pragma unroll
            for (int r = 0; r < 4; ++r)
                C[(size_t)(grow + r)*N + gcol] = acc[i][j][r] + badd;
        }
    }
}

// ---------------- fused main QKV GEMM: Bt = [WTq;WTk;WTv] (3072 x 1024) ----
// C base = Qb; Q/K/V outputs contiguous, each OUTN elems. bf16 out.
__global__ __launch_bounds__(256) void gemm_qkv(
    const unsigned short* __restrict__ A, const unsigned short* __restrict__ Bt,
    const float* __restrict__ bq, const float* __restrict__ bk, const float* __restrict__ bv,
    unsigned short* __restrict__ C)
{
    __shared__ short ldsA[128*32];
    __shared__ short ldsB[128*32];
    const int lane = threadIdx.x & 63, w = threadIdx.x >> 6;
    const int wr = w >> 1, wc = w & 1;
    const int lq = lane >> 4, lm = lane & 15;
    const int m0 = blockIdx.y * 128, n0g = blockIdx.x * 128;
    const int buf = n0g >> 10;
    const float* bias = (buf == 0) ? bq : (buf == 1) ? bk : bv;
    unsigned short* Cb = C + (size_t)buf * OUTN;
    f32x4 acc[4][4];
    #pragma unroll
    for (int i = 0; i < 4; ++i)
        #pragma unroll
        for (int j = 0; j < 4; ++j) acc[i][j] = (f32x4){0.f,0.f,0.f,0.f};
    gemm_core(A, Bt, m0, n0g, DM, ldsA, ldsB, acc);
    #pragma unroll
    for (int j = 0; j < 4; ++j) {
        const int gcol = (n0g & 1023) + wc*64 + j*16 + lm;
        const float badd = bias[gcol];
        #pragma unroll
        for (int i = 0; i < 4; ++i) {
            const int grow = m0 + wr*64 + i*16 + lq*4;
            #pragma unroll
            for (int r = 0; r < 4; ++r)
                Cb[(size_t)(grow + r)*DM + gcol] = f2bf(acc[i][j][r] + badd);
        }
    }
}

// ---------------- grouped expert QKV GEMM (2 experts per chunk) ----------
// grid (8, 40, 3): z selects {q,k,v}; y-block / 20 selects expert-in-chunk.
__global__ __launch_bounds__(256) void gemm_eqkv(
    const unsigned short* __restrict__ A,
    const unsigned short* __restrict__ eWTq, const unsigned short* __restrict__ eWTk,
    const unsigned short* __restrict__ eWTv,
    unsigned short* __restrict__ Cq, unsigned short* __restrict__ Ck,
    unsigned short* __restrict__ Cv, int ebase)
{
    __shared__ short ldsA[128*32];
    __shared__ short ldsB[128*32];
    const int lane = threadIdx.x & 63, w = threadIdx.x >> 6;
    const int wr = w >> 1, wc = w & 1;
    const int lq = lane >> 4, lm = lane & 15;
    const int z = blockIdx.z;
    const int eloc = blockIdx.y / 20;
    const unsigned short* Bt =
        ((z == 0) ? eWTq : (z == 1) ? eWTk : eWTv) + (size_t)(ebase + eloc) * (1024l*1024l);
    unsigned short* C = (z == 0) ? Cq : (z == 1) ? Ck : Cv;
    const int m0 = blockIdx.y * 128, n0 = blockIdx.x * 128;
    f32x4 acc[4][4];
    #pragma unroll
    for (int i = 0; i < 4; ++i)
        #pragma unroll
        for (int j = 0; j < 4; ++j) acc[i][j] = (f32x4){0.f,0.f,0.f,0.f};
    gemm_core(A, Bt, m0, n0, DM, ldsA, ldsB, acc);
    #pragma unroll
    for (int j = 0; j < 4; ++j) {
        const int gcol = n0 + wc*64 + j*16 + lm;
        #pragma unroll
        for (int i = 0; i < 4; ++i) {
            const int grow = m0 + wr*64 + i*16 + lq*4;
            #pragma unroll
            for (int r = 0; r < 4; ++r)
                C[(size_t)(grow + r)*DM + gcol] = f2bf(acc[i][j][r]);
        }
    }
}

// ---------------- grouped expert output GEMM (bf16 out) ------------------
__global__ __launch_bounds__(256) void gemm_eout(
    const unsigned short* __restrict__ A, const unsigned short* __restrict__ eWTo,
    unsigned short* __restrict__ C, int ebase)
{
    __shared__ short ldsA[128*32];
    __shared__ short ldsB[128*32];
    const int lane = threadIdx.x & 63, w = threadIdx.x >> 6;
    const int wr = w >> 1, wc = w & 1;
    const int lq = lane >> 4, lm = lane & 15;
    const int eloc = blockIdx.y / 20;
    const unsigned short* Bt = eWTo + (size_t)(ebase + eloc) * (1024l*1024l);
    const int m0 = blockIdx.y * 128, n0 = blockIdx.x * 128;
    f32x4 acc[4][4];
    #pragma unroll
    for (int i = 0; i < 4; ++i)
        #pragma unroll
        for (int j = 0; j < 4; ++j) acc[i][j] = (f32x4){0.f,0.f,0.f,0.f};
    gemm_core(A, Bt, m0, n0, DM, ldsA, ldsB, acc);
    #pragma unroll
    for (int j = 0; j < 4; ++j) {
        const int gcol = n0 + wc*64 + j*16 + lm;
        #pragma unroll
        for (int i = 0; i < 4; ++i) {
            const int grow = m0 + wr*64 + i*16 + lq*4;
            #pragma unroll
            for (int r = 0; r < 4; ++r)
                C[(size_t)(grow + r)*DM + gcol] = f2bf(acc[i][j][r]);
        }
    }
}

// ---------------- MFMA flash attention (bf16 in/out, fp32 softmax) ------
// V-transpose LDS swizzle: f(d,k) = ((k>>3) ^ (d>>3) ^ d) & 7, applied on
// BOTH write and read. The previous f = (k>>3)^(d&7) had wave-constant
// (k>>3) and u-constant (d&7) per scalar store -> 32 lanes on 2 banks
// (16-way HD=64 / 32-way HD=128, SQ_LDS_BANK_CONFLICT=3.5e7). XOR-ing in
// (d>>3)=scg spreads each 32-lane phase across all 8 bank groups; the
// remaining 2 lanes/bank are same-dword byte pairs (free).
template<int HD>
__global__ __launch_bounds__(256) void flash_mfma(
    const unsigned short* __restrict__ Q, const unsigned short* __restrict__ K,
    const unsigned short* __restrict__ V, unsigned short* __restrict__ O,
    int rows, float scale)
{
    constexpr int QT = 64, KT = 64;
    constexpr int PADQ = HD + 8;
    constexpr int NKT = HD / 32;
    constexpr int NDT = HD / 16;
    constexpr int CG  = HD / 8;
    constexpr int RPR = 256 / CG;
    __shared__ __align__(16) unsigned short qs[QT * PADQ];
    __shared__ __align__(16) unsigned short ks[KT * PADQ];
    __shared__ __align__(16) unsigned short vt[HD * KT];
    __shared__ __align__(16) unsigned short pP[4][16 * 72];
    const int t = threadIdx.x, lane = t & 63, w = t >> 6;
    const int lm = lane & 15, quad = lane >> 4;
    const int q0 = blockIdx.x * QT;
    const long base = (long)blockIdx.z * rows * DM + (long)blockIdx.y * HD;
    const int srow = t / CG, scg = t % CG;

    #pragma unroll
    for (int r = 0; r < QT / RPR; ++r) {
        int row = srow + r * RPR;
        *(bf16x8*)&qs[row * PADQ + scg * 8] =
            *(const bf16x8*)&Q[base + (long)(q0 + row) * DM + scg * 8];
    }
    __syncthreads();
    bf16x8 aQ[NKT];
    #pragma unroll
    for (int kk = 0; kk < NKT; ++kk)
        aQ[kk] = *(const bf16x8*)&qs[(w * 16 + lm) * PADQ + kk * 32 + quad * 8];

    float m4[4], l4[4];
    #pragma unroll
    for (int r = 0; r < 4; ++r) { m4[r] = -1e30f; l4[r] = 0.f; }
    f32x4 aco[NDT];
    #pragma unroll
    for (int d = 0; d < NDT; ++d) aco[d] = (f32x4){0.f,0.f,0.f,0.f};

    for (int k0 = 0; k0 < rows; k0 += KT) {
        __syncthreads();
        #pragma unroll
        for (int r = 0; r < KT / RPR; ++r) {
            int row = srow + r * RPR;
            *(bf16x8*)&ks[row * PADQ + scg * 8] =
                *(const bf16x8*)&K[base + (long)(k0 + row) * DM + scg * 8];
            bf16x8 vv = *(const bf16x8*)&V[base + (long)(k0 + row) * DM + scg * 8];
            #pragma unroll
            for (int u = 0; u < 8; ++u) {
                int d = scg * 8 + u;
                vt[d * KT + ((((row >> 3) ^ (d >> 3) ^ d) & 7)) * 8 + (row & 7)] = ((short*)&vv)[u];
            }
        }
        __syncthreads();
        f32x4 sc[4];
        #pragma unroll
        for (int n = 0; n < 4; ++n) {
            f32x4 c = (f32x4){0.f,0.f,0.f,0.f};
            #pragma unroll
            for (int kk = 0; kk < NKT; ++kk) {
                bf16x8 bK = *(const bf16x8*)&ks[(n * 16 + lm) * PADQ + kk * 32 + quad * 8];
                c = __builtin_amdgcn_mfma_f32_16x16x32_bf16(aQ[kk], bK, c, 0, 0, 0);
            }
            #pragma unroll
            for (int r = 0; r < 4; ++r) c[r] *= scale;
            sc[n] = c;
        }
        float alpha[4];
        #pragma unroll
        for (int r = 0; r < 4; ++r) {
            float mx = fmaxf(fmaxf(sc[0][r], sc[1][r]), fmaxf(sc[2][r], sc[3][r]));
            #pragma unroll
            for (int off = 1; off < 16; off <<= 1)
                mx = fmaxf(mx, __shfl_xor(mx, off, 64));
            float mnew = fmaxf(m4[r], mx);
            alpha[r] = __expf(m4[r] - mnew);
            m4[r] = mnew;
            float s = 0.f;
            #pragma unroll
            for (int n = 0; n < 4; ++n) {
                float p = __expf(sc[n][r] - mnew);
                sc[n][r] = p; s += p;
            }
            #pragma unroll
            for (int off = 1; off < 16; off <<= 1)
                s += __shfl_xor(s, off, 64);
            l4[r] = l4[r] * alpha[r] + s;
        }
        #pragma unroll
        for (int n = 0; n < 4; ++n)
            #pragma unroll
            for (int r = 0; r < 4; ++r)
                pP[w][(quad * 4 + r) * 72 + n * 16 + lm] = f2bf(sc[n][r]);
        #pragma unroll
        for (int d = 0; d < NDT; ++d)
            #pragma unroll
            for (int r = 0; r < 4; ++r) aco[d][r] *= alpha[r];
        #pragma unroll
        for (int d = 0; d < NDT; ++d) {
            #pragma unroll
            for (int kk = 0; kk < 2; ++kk) {
                bf16x8 aP = *(const bf16x8*)&pP[w][lm * 72 + kk * 32 + quad * 8];
                int dd = d * 16 + lm;
                int jb = kk * 4 + quad;
                bf16x8 bV = *(const bf16x8*)&vt[dd * KT + (((jb ^ (dd >> 3) ^ dd) & 7) * 8)];
                aco[d] = __builtin_amdgcn_mfma_f32_16x16x32_bf16(aP, bV, aco[d], 0, 0, 0);
            }
        }
    }
    #pragma unroll
    for (int r = 0; r < 4; ++r) l4[r] = 1.f / l4[r];
    #pragma unroll
    for (int d = 0; d < NDT; ++d)
        #pragma unroll
        for (int r = 0; r < 4; ++r)
            O[base + (long)(q0 + w * 16 + quad * 4 + r) * DM + d * 16 + lm] =
                f2bf(aco[d][r] * l4[r]);
}

// ---------------- weight transpose + fp32->bf16 -------------------------
__global__ __launch_bounds__(256) void transpose_bf16(
    const float* __restrict__ src, unsigned short* __restrict__ dst)
{
    __shared__ float tile[32][33];
    const long mb = (long)blockIdx.z * (1024l*1024l);
    const int tx = threadIdx.x & 31, ty = threadIdx.x >> 5;
    const int r0 = blockIdx.y * 32, c0 = blockIdx.x * 32;
    #pragma unroll
    for (int rr = ty; rr < 32; rr += 8)
        tile[rr][tx] = src[mb + (long)(r0+rr)*1024 + c0 + tx];
    __syncthreads();
    #pragma unroll
    for (int rr = ty; rr < 32; rr += 8)
        dst[mb + (long)(c0+rr)*1024 + r0 + tx] = f2bf(tile[tx][rr]);
}

// ---------------- flat fp32 -> bf16 convert ----------------------------
__global__ __launch_bounds__(256) void convert_bf16(
    const float* __restrict__ src, unsigned short* __restrict__ dst, long n)
{
    long i = ((long)blockIdx.x*256 + threadIdx.x)*4;
    if (i >= n) return;
    float4 v = *(const float4*)&src[i];
    ushort4 o = { f2bf(v.x), f2bf(v.y), f2bf(v.z), f2bf(v.w) };
    *(ushort4*)&dst[i] = o;
}

// ---------------- Residual + LayerNorm (fp32 out) -----------------------
__global__ __launch_bounds__(256) void ln_residual(
    const float* __restrict__ X, const float* __restrict__ R,
    const float* __restrict__ gam, const float* __restrict__ bet,
    float* __restrict__ Y)
{
    const long row = blockIdx.x;
    const int t = threadIdx.x;
    float4 xv = *(const float4*)&X[row*DM + t*4];
    float4 rv = *(const float4*)&R[row*DM + t*4];
    float v0=xv.x+rv.x, v1=xv.y+rv.y, v2=xv.z+rv.z, v3=xv.w+rv.w;
    float s  = v0+v1+v2+v3;
    float s2 = v0*v0+v1*v1+v2*v2+v3*v3;
    #pragma unroll
    for (int off = 32; off > 0; off >>= 1) {
        s  += __shfl_down(s,  off, 64);
        s2 += __shfl_down(s2, off, 64);
    }
    __shared__ float red[8];
    __shared__ float mv[2];
    const int wid = t >> 6;
    if ((t & 63) == 0) { red[wid] = s; red[4+wid] = s2; }
    __syncthreads();
    if (t == 0) {
        float S  = red[0]+red[1]+red[2]+red[3];
        float S2 = red[4]+red[5]+red[6]+red[7];
        float mean = S * (1.f/DM);
        float var  = S2 * (1.f/DM) - mean*mean;
        mv[0] = mean; mv[1] = rsqrtf(var + 1e-5f);
    }
    __syncthreads();
    float mean = mv[0], inv = mv[1];
    float4 g4 = *(const float4*)&gam[t*4];
    float4 b4 = *(const float4*)&bet[t*4];
    float4 o4;
    o4.x = (v0-mean)*inv*g4.x + b4.x;
    o4.y = (v1-mean)*inv*g4.y + b4.y;
    o4.z = (v2-mean)*inv*g4.z + b4.z;
    o4.w = (v3-mean)*inv*g4.w + b4.w;
    *(float4*)&Y[row*DM + t*4] = o4;
}

// ---------------- Combine (gather expert outs) + LN2 --------------------
__global__ __launch_bounds__(256) void combine_ln(
    const float* __restrict__ X1, const unsigned short* __restrict__ Eout,
    const int* __restrict__ e1, const int* __restrict__ pos1,
    const int* __restrict__ keep1, const float* __restrict__ g1,
    const int* __restrict__ e2, const int* __restrict__ pos2,
    const int* __restrict__ keep2, const float* __restrict__ g2,
    const float* __restrict__ gam, const float* __restrict__ bet,
    float* __restrict__ Y)
{
    const long row = blockIdx.x;
    const int b = (int)(row >> 10);
    const int t = threadIdx.x;
    float4 xv = *(const float4*)&X1[row*DM + t*4];
    float v0=xv.x, v1=xv.y, v2=xv.z, v3=xv.w;
    const float w1 = keep1[row] ? g1[row] : 0.f;
    const float w2 = keep2[row] ? g2[row] : 0.f;
    if (w1 != 0.f) {
        ushort4 u = *(const ushort4*)&Eout[(((size_t)e1[row]*BATCH + b)*CAPE + pos1[row])*DM + t*4];
        v0 += w1*bf2f(u.x); v1 += w1*bf2f(u.y); v2 += w1*bf2f(u.z); v3 += w1*bf2f(u.w);
    }
    if (w2 != 0.f) {
        ushort4 u = *(const ushort4*)&Eout[(((size_t)e2[row]*BATCH + b)*CAPE + pos2[row])*DM + t*4];
        v0 += w2*bf2f(u.x); v1 += w2*bf2f(u.y); v2 += w2*bf2f(u.z); v3 += w2*bf2f(u.w);
    }
    float s  = v0+v1+v2+v3;
    float s2 = v0*v0+v1*v1+v2*v2+v3*v3;
    #pragma unroll
    for (int off = 32; off > 0; off >>= 1) {
        s  += __shfl_down(s,  off, 64);
        s2 += __shfl_down(s2, off, 64);
    }
    __shared__ float red[8];
    __shared__ float mv[2];
    const int wid = t >> 6;
    if ((t & 63) == 0) { red[wid] = s; red[4+wid] = s2; }
    __syncthreads();
    if (t == 0) {
        float S  = red[0]+red[1]+red[2]+red[3];
        float S2 = red[4]+red[5]+red[6]+red[7];
        float mean = S * (1.f/DM);
        float var  = S2 * (1.f/DM) - mean*mean;
        mv[0] = mean; mv[1] = rsqrtf(var + 1e-5f);
    }
    __syncthreads();
    float mean = mv[0], inv = mv[1];
    float4 g4 = *(const float4*)&gam[t*4];
    float4 b4 = *(const float4*)&bet[t*4];
    float4 o4;
    o4.x = (v0-mean)*inv*g4.x + b4.x;
    o4.y = (v1-mean)*inv*g4.y + b4.y;
    o4.z = (v2-mean)*inv*g4.z + b4.z;
    o4.w = (v3-mean)*inv*g4.w + b4.w;
    *(float4*)&Y[row*DM + t*4] = o4;
}

// ---------------- Gate: 512 blocks x 4 waves, 1 wave per token ----------
__global__ __launch_bounds__(256) void gate_kernel(
    const float* __restrict__ X1, const float* __restrict__ gW,
    int* __restrict__ e1, int* __restrict__ e2,
    float* __restrict__ g1, float* __restrict__ g2,
    float* __restrict__ accum)
{
    const int t = threadIdx.x, l = t & 63, w = t >> 6;
    const int gwave = blockIdx.x * 4 + w;     // 0..2047
    float zacc = 0.f, pacc[8], facc[8];
    #pragma unroll
    for (int e = 0; e < 8; ++e) { pacc[e] = 0.f; facc[e] = 0.f; }

    for (int tok = gwave; tok < NTOK; tok += 2048) {
        const float* xr = X1 + (long)tok*DM;
        float part[8];
        #pragma unroll
        for (int e = 0; e < 8; ++e) part[e] = 0.f;
        #pragma unroll
        for (int pass = 0; pass < 4; ++pass) {
            const int i0 = pass*256 + l*4;
            float4 xv = *(const float4*)&xr[i0];
            const float xs[4] = {xv.x, xv.y, xv.z, xv.w};
            #pragma unroll
            for (int u = 0; u < 4; ++u) {
                float4 w0 = *(const float4*)&gW[(i0+u)*8];
                float4 w1 = *(const float4*)&gW[(i0+u)*8+4];
                part[0]+=xs[u]*w0.x; part[1]+=xs[u]*w0.y; part[2]+=xs[u]*w0.z; part[3]+=xs[u]*w0.w;
                part[4]+=xs[u]*w1.x; part[5]+=xs[u]*w1.y; part[6]+=xs[u]*w1.z; part[7]+=xs[u]*w1.w;
            }
        }
        #pragma unroll
        for (int e = 0; e < 8; ++e) {
            float v = part[e];
            #pragma unroll
            for (int off = 32; off > 0; off >>= 1) v += __shfl_down(v, off, 64);
            part[e] = v;
        }
        if (l == 0) {
            float mx = part[0];
            #pragma unroll
            for (int e = 1; e < 8; ++e) mx = fmaxf(mx, part[e]);
            float p[8]; float sum = 0.f;
            #pragma unroll
            for (int e = 0; e < 8; ++e) { p[e] = __expf(part[e]-mx); sum += p[e]; }
            float lse = mx + __logf(sum);
            float isum = 1.f/sum;
            #pragma unroll
            for (int e = 0; e < 8; ++e) { p[e] *= isum; pacc[e] += p[e]; }
            int b1 = 0;
            #pragma unroll
            for (int e = 1; e < 8; ++e) if (p[e] > p[b1]) b1 = e;
            int b2 = (b1 == 0) ? 1 : 0;
            #pragma unroll
            for (int e = 0; e < 8; ++e) if (e != b1 && e != b2 && p[e] > p[b2]) b2 = e;
            e1[tok] = b1; e2[tok] = b2; g1[tok] = p[b1]; g2[tok] = p[b2];
            zacc += lse*lse;
            facc[b1] += 1.f;
        }
    }
    __shared__ float red[4][17];
    if (l == 0) {
        red[w][0] = zacc;
        #pragma unroll
        for (int e = 0; e < 8; ++e) { red[w][1+e] = pacc[e]; red[w][9+e] = facc[e]; }
    }
    __syncthreads();
    if (t < 17)
        atomicAdd(&accum[t], red[0][t] + red[1][t] + red[2][t] + red[3][t]);
}

// ---------------- Routing scan ------------------------------------------
__global__ __launch_bounds__(64) void route_scan(
    const int* __restrict__ e1, const int* __restrict__ e2,
    const float* __restrict__ g2,
    int* __restrict__ pos1, int* __restrict__ keep1,
    int* __restrict__ pos2, int* __restrict__ keep2,
    int* __restrict__ slotmap)
{
    const int b = blockIdx.x;
    const int l = threadIdx.x;
    __shared__ int cnt[8];
    if (l < 8) cnt[l] = 0;
    __syncthreads();
    for (int slot = 0; slot < 2; ++slot) {
        const int* eArr = slot ? e2 : e1;
        for (int c = 0; c < SEQ/64; ++c) {
            const int tk = b*SEQ + c*64 + l;
            const int e = eArr[tk];
            const bool valid = slot ? (g2[tk] > 0.2f) : true;
            unsigned long long mymask = 0ull; int addmine = 0;
            #pragma unroll
            for (int ee = 0; ee < 8; ++ee) {
                unsigned long long bm = __ballot(valid && (e == ee));
                if (e == ee) mymask = bm;
                if (l == ee) addmine = (int)__popcll(bm);
            }
            const int p  = cnt[e] + (int)__popcll(mymask & ((1ull << l) - 1ull));
            const int kp = (valid && p < CAPE) ? 1 : 0;
            const int pc = p < CAPE ? p : (CAPE-1);
            if (slot == 0) { pos1[tk] = pc; keep1[tk] = kp; }
            else           { pos2[tk] = pc; keep2[tk] = kp; }
            if (kp) slotmap[(e*BATCH + b)*CAPE + pc] = tk;
            __syncthreads();
            if (l < 8) cnt[l] += addmine;
            __syncthreads();
        }
    }
}

// ---------------- Gather expert inputs for a 2-expert chunk -------------
__global__ __launch_bounds__(256) void gather_chunk(
    const float* __restrict__ X1, const int* __restrict__ slotmap,
    unsigned short* __restrict__ Ein, int ebase)
{
    const int slot = blockIdx.x;              // [eloc][b][p], eloc in 0..1
    const int t = threadIdx.x;
    const int tok = slotmap[ebase*(BATCH*CAPE) + slot];
    float4 v4 = make_float4(0.f, 0.f, 0.f, 0.f);
    if (tok >= 0) v4 = *(const float4*)&X1[(long)tok*DM + t*4];
    ushort4 o = { f2bf(v4.x), f2bf(v4.y), f2bf(v4.z), f2bf(v4.w) };
    *(ushort4*)&Ein[(long)slot*DM + t*4] = o;
}

// ---------------- Loss scalars ------------------------------------------
__global__ void finalize_loss(const float* __restrict__ accum, float* __restrict__ out)
{
    float z = accum[0] * (1.0f/NTOK);
    float s = 0.f;
    for (int e = 0; e < 8; ++e)
        s += (accum[1+e] * (1.0f/NTOK)) * (accum[9+e] * (1.0f/NTOK));
    float bal = 0.01f * 8.0f * s;
    float zl  = 0.001f * z;
    out[OUTN]   = bal + zl;
    out[OUTN+1] = bal;
    out[OUTN+2] = zl;
}

extern "C" void kernel_launch(void* const* d_in, const int* in_sizes, int n_in,
                              void* d_out, int out_size, void* d_ws, size_t ws_size,
                              hipStream_t stream)
{
    (void)in_sizes; (void)n_in; (void)out_size; (void)ws_size;
    const float* x    = (const float*)d_in[0];
    const float* Wq   = (const float*)d_in[1];
    const float* Wk   = (const float*)d_in[2];
    const float* Wv   = (const float*)d_in[3];
    const float* Wo   = (const float*)d_in[4];
    const float* bq   = (const float*)d_in[5];
    const float* bk   = (const float*)d_in[6];
    const float* bv   = (const float*)d_in[7];
    const float* bo   = (const float*)d_in[8];
    const float* ln1g = (const float*)d_in[9];
    const float* ln1b = (const float*)d_in[10];
    const float* ln2g = (const float*)d_in[11];
    const float* ln2b = (const float*)d_in[12];
    const float* gW   = (const float*)d_in[13];
    const float* eWq  = (const float*)d_in[14];
    const float* eWk  = (const float*)d_in[15];
    const float* eWv  = (const float*)d_in[16];
    const float* eWo  = (const float*)d_in[17];
    float* out = (float*)d_out;

    char* ws = (char*)d_ws;
    const size_t MB = 1048576;
    const long MATE = 1024l*1024l;
    // ---- layout ----
    // 0-72 MB: bf16 transposed weights
    unsigned short* WTq  = (unsigned short*)(ws);           // 3 contiguous for fused QKV
    unsigned short* WTk  = WTq + 1*MATE;
    unsigned short* WTv  = WTq + 2*MATE;
    unsigned short* WTo  = WTq + 3*MATE;
    unsigned short* eWTq = WTq + 4*MATE;
    unsigned short* eWTk = WTq + 12*MATE;
    unsigned short* eWTv = WTq + 20*MATE;
    unsigned short* eWTo = WTq + 28*MATE;
    // 72-74 MB: routing/meta
    int*   e1i   = (int*)(ws + 72*MB);
    int*   e2i   = e1i + NTOK;
    int*   pos1  = e1i + 2*NTOK;
    int*   pos2  = e1i + 3*NTOK;
    int*   keep1 = e1i + 4*NTOK;
    int*   keep2 = e1i + 5*NTOK;
    int*   slotmap = e1i + 6*NTOK;                          // 20480 ints
    float* g1f   = (float*)(e1i + 6*NTOK + NE*BATCH*CAPE);
    float* g2f   = g1f + NTOK;
    float* accum = g2f + NTOK;                              // 17 floats
    // stage-1 buffers
    unsigned short* xb = (unsigned short*)(ws + 74*MB);     // 16 MB
    unsigned short* ob = (unsigned short*)(ws + 90*MB);     // 16 MB
    unsigned short* Qb = (unsigned short*)(ws + 106*MB);    // Q/K/V contiguous 48 MB
    float* Pf = (float*)(ws + 106*MB);                      // fp32 Wo out (aliases Q/K)
    float* x1 = (float*)(ws + 154*MB);                      // 32 MB
    // expert phase (stage-1 region 74-154 dead after ln1)
    unsigned short* eoutAll = (unsigned short*)(ws + 74*MB);   // 40 MB: [8][8][320][1024]
    unsigned short* Einb = (unsigned short*)(ws + 114*MB);     // 10 MB (2-expert chunk)
    unsigned short* eqb  = (unsigned short*)(ws + 124*MB);
    unsigned short* ekb  = (unsigned short*)(ws + 134*MB);
    unsigned short* evb  = (unsigned short*)(ws + 144*MB);
    unsigned short* eob  = Einb;                               // alias (Ein dead after qkv)

    dim3 blk(256);
    dim3 tgrid(32, 32, 1), tgrid8(32, 32, 8);

    // ---- weight prep ----
    transpose_bf16<<<tgrid,  blk, 0, stream>>>(Wq,  WTq);
    transpose_bf16<<<tgrid,  blk, 0, stream>>>(Wk,  WTk);
    transpose_bf16<<<tgrid,  blk, 0, stream>>>(Wv,  WTv);
    transpose_bf16<<<tgrid,  blk, 0, stream>>>(Wo,  WTo);
    transpose_bf16<<<tgrid8, blk, 0, stream>>>(eWq, eWTq);
    transpose_bf16<<<tgrid8, blk, 0, stream>>>(eWk, eWTk);
    transpose_bf16<<<tgrid8, blk, 0, stream>>>(eWv, eWTv);
    transpose_bf16<<<tgrid8, blk, 0, stream>>>(eWo, eWTo);
    convert_bf16<<<NTOK, blk, 0, stream>>>(x, xb, OUTN);

    // ---- stage 1: MHA + LN1 ----
    gemm_qkv<<<dim3(3*DM/128, NTOK/128), blk, 0, stream>>>(xb, WTq, bq, bk, bv, Qb);
    flash_mfma<HDIM1><<<dim3(SEQ/64, NH1, BATCH), blk, 0, stream>>>(
        Qb, Qb + OUTN, Qb + 2*OUTN, ob, SEQ, 0.125f);
    gemm_bt_f32<<<dim3(DM/128, NTOK/128), blk, 0, stream>>>(ob, WTo, bo, Pf, DM, DM);
    ln_residual<<<NTOK, blk, 0, stream>>>(x, Pf, ln1g, ln1b, x1);

    // ---- gate + routing ----
    hipMemsetAsync(accum, 0, 17*sizeof(float), stream);
    hipMemsetAsync(slotmap, 0xFF, NE*BATCH*CAPE*sizeof(int), stream);
    gate_kernel<<<512, blk, 0, stream>>>(x1, gW, e1i, e2i, g1f, g2f, accum);
    route_scan<<<BATCH, dim3(64), 0, stream>>>(e1i, e2i, g2f, pos1, keep1, pos2, keep2, slotmap);

    // ---- experts: 4 chunks of 2 ----
    for (int c = 0; c < 4; ++c) {
        const int ebase = c*2;
        gather_chunk<<<2*BATCH*CAPE, blk, 0, stream>>>(x1, slotmap, Einb, ebase);
        gemm_eqkv<<<dim3(DM/128, 2*BATCH*CAPE/128, 3), blk, 0, stream>>>(
            Einb, eWTq, eWTk, eWTv, eqb, ekb, evb, ebase);
        flash_mfma<HDIM2><<<dim3(CAPE/64, NH2, 2*BATCH), blk, 0, stream>>>(
            eqb, ekb, evb, eob, CAPE, 0.088388347648318447f);
        gemm_eout<<<dim3(DM/128, 2*BATCH*CAPE/128), blk, 0, stream>>>(
            eob, eWTo, eoutAll + (size_t)ebase*ECB, ebase);
    }

    // ---- combine + final LN + losses ----
    combine_ln<<<NTOK, blk, 0, stream>>>(x1, eoutAll, e1i, pos1, keep1, g1f,
                                         e2i, pos2, keep2, g2f, ln2g, ln2b, out);
    finalize_loss<<<1, 1, 0, stream>>>(accum, out);
}

// Round 2
// 1030.013 us; speedup vs baseline: 1.1231x; 1.0909x over previous
//
#include <hip/hip_runtime.h>
#include <hip/hip_bf16.h>
#include <math.h>

#define DM    1024
#define NH1   16
#define HDIM1 64
#define NH2   8
#define HDIM2 128
#define NE    8
#define CAPE  320
#define BATCH 8
#define SEQ   1024
#define NTOK  (BATCH*SEQ)        /* 8192 */
#define OUTN  ((long)NTOK*DM)    /* 8388608 */
#define ECB   ((long)BATCH*CAPE*DM)  /* 2,621,440 elems per expert */

typedef short bf16x8 __attribute__((ext_vector_type(8)));
typedef float f32x4  __attribute__((ext_vector_type(4)));

__device__ __forceinline__ unsigned short f2bf(float f) {
    __hip_bfloat16 h = __float2bfloat16(f);
    return *reinterpret_cast<unsigned short*>(&h);
}
__device__ __forceinline__ float bf2f(unsigned short u) {
    unsigned int x = ((unsigned int)u) << 16;
    return __builtin_bit_cast(float, x);
}

__device__ __forceinline__ void async16(const void* g, void* lds) {
    __builtin_amdgcn_global_load_lds(
        (const __attribute__((address_space(1))) unsigned int*)g,
        (__attribute__((address_space(3))) unsigned int*)lds, 16, 0, 0);
}

// ---------------- shared GEMM core: 128x128 tile, BK=32, 4 waves --------
// acc[i][j] accumulates C-tile (wr,wc wave grid). A[M,K], Bt[N,K] bf16.
__device__ __forceinline__ void gemm_core(
    const unsigned short* __restrict__ A, const unsigned short* __restrict__ Bt,
    int m0, int n0, int K, short* ldsA, short* ldsB, f32x4 (&acc)[4][4])
{
    const int t    = threadIdx.x;
    const int lane = t & 63, w = t >> 6;
    const int wr = w >> 1, wc = w & 1;
    const int lq = lane >> 4, lm = lane & 15;
    const int srow = w*16 + (lane >> 2);
    const int skc  = (lane & 3) * 8;
    for (int kb = 0; kb < K; kb += 32) {
        #pragma unroll
        for (int p = 0; p < 2; ++p) {
            async16(A  + (size_t)(m0 + srow + p*64)*K + kb + skc,
                    &ldsA[(w*16 + p*64)*32]);
            async16(Bt + (size_t)(n0 + srow + p*64)*K + kb + skc,
                    &ldsB[(w*16 + p*64)*32]);
        }
        __syncthreads();
        bf16x8 aF[4], bF[4];
        #pragma unroll
        for (int i = 0; i < 4; ++i)
            aF[i] = *(const bf16x8*)&ldsA[(wr*64 + i*16 + lm)*32 + lq*8];
        #pragma unroll
        for (int j = 0; j < 4; ++j)
            bF[j] = *(const bf16x8*)&ldsB[(wc*64 + j*16 + lm)*32 + lq*8];
        #pragma unroll
        for (int i = 0; i < 4; ++i)
            #pragma unroll
            for (int j = 0; j < 4; ++j)
                acc[i][j] = __builtin_amdgcn_mfma_f32_16x16x32_bf16(aF[i], bF[j], acc[i][j], 0, 0, 0);
        __syncthreads();
    }
}

// ---------------- plain GEMM (fp32 out, bias) — used for Wo projection ----
__global__ __launch_bounds__(256) void gemm_bt_f32(
    const unsigned short* __restrict__ A, const unsigned short* __restrict__ Bt,
    const float* __restrict__ bias, float* __restrict__ C, int N, int K)
{
    __shared__ short ldsA[128*32];
    __shared__ short ldsB[128*32];
    const int lane = threadIdx.x & 63, w = threadIdx.x >> 6;
    const int wr = w >> 1, wc = w & 1;
    const int lq = lane >> 4, lm = lane & 15;
    const int m0 = blockIdx.y * 128, n0 = blockIdx.x * 128;
    f32x4 acc[4][4];
    #pragma unroll
    for (int i = 0; i < 4; ++i)
        #pragma unroll
        for (int j = 0; j < 4; ++j) acc[i][j] = (f32x4){0.f,0.f,0.f,0.f};
    gemm_core(A, Bt, m0, n0, K, ldsA, ldsB, acc);
    #pragma unroll
    for (int j = 0; j < 4; ++j) {
        const int gcol = n0 + wc*64 + j*16 + lm;
        const float badd = bias ? bias[gcol] : 0.f;
        #pragma unroll
        for (int i = 0; i < 4; ++i) {
            const int grow = m0 + wr*64 + i*16 + lq*4;
            #pragma unroll
            for (int r = 0; r < 4; ++r)
                C[(size_t)(grow + r)*N + gcol] = acc[i][j][r] + badd;
        }
    }
}

// ---------------- fused main QKV GEMM: Bt = [WTq;WTk;WTv] (3072 x 1024) ----
// C base = Qb; Q/K/V outputs contiguous, each OUTN elems. bf16 out.
__global__ __launch_bounds__(256) void gemm_qkv(
    const unsigned short* __restrict__ A, const unsigned short* __restrict__ Bt,
    const float* __restrict__ bq, const float* __restrict__ bk, const float* __restrict__ bv,
    unsigned short* __restrict__ C)
{
    __shared__ short ldsA[128*32];
    __shared__ short ldsB[128*32];
    const int lane = threadIdx.x & 63, w = threadIdx.x >> 6;
    const int wr = w >> 1, wc = w & 1;
    const int lq = lane >> 4, lm = lane & 15;
    const int m0 = blockIdx.y * 128, n0g = blockIdx.x * 128;
    const int buf = n0g >> 10;
    const float* bias = (buf == 0) ? bq : (buf == 1) ? bk : bv;
    unsigned short* Cb = C + (size_t)buf * OUTN;
    f32x4 acc[4][4];
    #pragma unroll
    for (int i = 0; i < 4; ++i)
        #pragma unroll
        for (int j = 0; j < 4; ++j) acc[i][j] = (f32x4){0.f,0.f,0.f,0.f};
    gemm_core(A, Bt, m0, n0g, DM, ldsA, ldsB, acc);
    #pragma unroll
    for (int j = 0; j < 4; ++j) {
        const int gcol = (n0g & 1023) + wc*64 + j*16 + lm;
        const float badd = bias[gcol];
        #pragma unroll
        for (int i = 0; i < 4; ++i) {
            const int grow = m0 + wr*64 + i*16 + lq*4;
            #pragma unroll
            for (int r = 0; r < 4; ++r)
                Cb[(size_t)(grow + r)*DM + gcol] = f2bf(acc[i][j][r] + badd);
        }
    }
}

// ---------------- grouped expert QKV GEMM (2 experts per chunk) ----------
// grid (8, 40, 3): z selects {q,k,v}; y-block / 20 selects expert-in-chunk.
__global__ __launch_bounds__(256) void gemm_eqkv(
    const unsigned short* __restrict__ A,
    const unsigned short* __restrict__ eWTq, const unsigned short* __restrict__ eWTk,
    const unsigned short* __restrict__ eWTv,
    unsigned short* __restrict__ Cq, unsigned short* __restrict__ Ck,
    unsigned short* __restrict__ Cv, int ebase)
{
    __shared__ short ldsA[128*32];
    __shared__ short ldsB[128*32];
    const int lane = threadIdx.x & 63, w = threadIdx.x >> 6;
    const int wr = w >> 1, wc = w & 1;
    const int lq = lane >> 4, lm = lane & 15;
    const int z = blockIdx.z;
    const int eloc = blockIdx.y / 20;
    const unsigned short* Bt =
        ((z == 0) ? eWTq : (z == 1) ? eWTk : eWTv) + (size_t)(ebase + eloc) * (1024l*1024l);
    unsigned short* C = (z == 0) ? Cq : (z == 1) ? Ck : Cv;
    const int m0 = blockIdx.y * 128, n0 = blockIdx.x * 128;
    f32x4 acc[4][4];
    #pragma unroll
    for (int i = 0; i < 4; ++i)
        #pragma unroll
        for (int j = 0; j < 4; ++j) acc[i][j] = (f32x4){0.f,0.f,0.f,0.f};
    gemm_core(A, Bt, m0, n0, DM, ldsA, ldsB, acc);
    #pragma unroll
    for (int j = 0; j < 4; ++j) {
        const int gcol = n0 + wc*64 + j*16 + lm;
        #pragma unroll
        for (int i = 0; i < 4; ++i) {
            const int grow = m0 + wr*64 + i*16 + lq*4;
            #pragma unroll
            for (int r = 0; r < 4; ++r)
                C[(size_t)(grow + r)*DM + gcol] = f2bf(acc[i][j][r]);
        }
    }
}

// ---------------- grouped expert output GEMM (bf16 out) ------------------
__global__ __launch_bounds__(256) void gemm_eout(
    const unsigned short* __restrict__ A, const unsigned short* __restrict__ eWTo,
    unsigned short* __restrict__ C, int ebase)
{
    __shared__ short ldsA[128*32];
    __shared__ short ldsB[128*32];
    const int lane = threadIdx.x & 63, w = threadIdx.x >> 6;
    const int wr = w >> 1, wc = w & 1;
    const int lq = lane >> 4, lm = lane & 15;
    const int eloc = blockIdx.y / 20;
    const unsigned short* Bt = eWTo + (size_t)(ebase + eloc) * (1024l*1024l);
    const int m0 = blockIdx.y * 128, n0 = blockIdx.x * 128;
    f32x4 acc[4][4];
    #pragma unroll
    for (int i = 0; i < 4; ++i)
        #pragma unroll
        for (int j = 0; j < 4; ++j) acc[i][j] = (f32x4){0.f,0.f,0.f,0.f};
    gemm_core(A, Bt, m0, n0, DM, ldsA, ldsB, acc);
    #pragma unroll
    for (int j = 0; j < 4; ++j) {
        const int gcol = n0 + wc*64 + j*16 + lm;
        #pragma unroll
        for (int i = 0; i < 4; ++i) {
            const int grow = m0 + wr*64 + i*16 + lq*4;
            #pragma unroll
            for (int r = 0; r < 4; ++r)
                C[(size_t)(grow + r)*DM + gcol] = f2bf(acc[i][j][r]);
        }
    }
}

// ---------------- MFMA flash attention (bf16 in/out, fp32 softmax) ------
// Occupancy + latency restructure (this round):
//  * Q is staged THROUGH ks (it was consumed into aQ regs and never re-read;
//    the loop-entry __syncthreads drains the lgkm reads before the first
//    K-tile overwrite). Dropping the dedicated qs buffer: LDS 35840->26624 B
//    (HD=64, 4->6 blocks/CU) and 60416->43008 B (HD=128, 2->3 blocks/CU).
//  * K/V tiles are reg-staged one tile ahead (T14 async split): per tile
//    {sync; ds_write from regs; sync; issue t+1 global loads; compute}.
//    The loads' only consumer is the next iteration's ds_write behind the
//    loop-top barrier, so HBM latency hides under QK/softmax/PV.
// V-transpose LDS swizzle f(d,k)=((k>>3)^(d>>3)^d)&7 on write and read
// (bank-conflict fix from last round, conflicts 3.5e7->9.5e6).
template<int HD>
__global__ __launch_bounds__(256) void flash_mfma(
    const unsigned short* __restrict__ Q, const unsigned short* __restrict__ K,
    const unsigned short* __restrict__ V, unsigned short* __restrict__ O,
    int rows, float scale)
{
    constexpr int QT = 64, KT = 64;
    constexpr int PADQ = HD + 8;
    constexpr int NKT = HD / 32;
    constexpr int NDT = HD / 16;
    constexpr int CG  = HD / 8;
    constexpr int RPR = 256 / CG;
    constexpr int NP  = KT / RPR;      // K/V rows per thread per tile (2 or 4)
    __shared__ __align__(16) unsigned short ks[KT * PADQ];
    __shared__ __align__(16) unsigned short vt[HD * KT];
    __shared__ __align__(16) unsigned short pP[4][16 * 72];
    const int t = threadIdx.x, lane = t & 63, w = t >> 6;
    const int lm = lane & 15, quad = lane >> 4;
    const int q0 = blockIdx.x * QT;
    const long base = (long)blockIdx.z * rows * DM + (long)blockIdx.y * HD;
    const int srow = t / CG, scg = t % CG;

    // ---- stage Q via ks, consume into registers ----
    #pragma unroll
    for (int r = 0; r < QT / RPR; ++r) {
        int row = srow + r * RPR;
        *(bf16x8*)&ks[row * PADQ + scg * 8] =
            *(const bf16x8*)&Q[base + (long)(q0 + row) * DM + scg * 8];
    }
    __syncthreads();
    bf16x8 aQ[NKT];
    #pragma unroll
    for (int kk = 0; kk < NKT; ++kk)
        aQ[kk] = *(const bf16x8*)&ks[(w * 16 + lm) * PADQ + kk * 32 + quad * 8];

    float m4[4], l4[4];
    #pragma unroll
    for (int r = 0; r < 4; ++r) { m4[r] = -1e30f; l4[r] = 0.f; }
    f32x4 aco[NDT];
    #pragma unroll
    for (int d = 0; d < NDT; ++d) aco[d] = (f32x4){0.f,0.f,0.f,0.f};

    // ---- preload K/V tile 0 into registers ----
    bf16x8 kr[NP], vr[NP];
    #pragma unroll
    for (int r = 0; r < NP; ++r) {
        int row = srow + r * RPR;
        kr[r] = *(const bf16x8*)&K[base + (long)row * DM + scg * 8];
        vr[r] = *(const bf16x8*)&V[base + (long)row * DM + scg * 8];
    }

    for (int k0 = 0; k0 < rows; k0 += KT) {
        __syncthreads();   // prev compute done with ks/vt (iter 0: aQ reads drained)
        #pragma unroll
        for (int r = 0; r < NP; ++r) {
            int row = srow + r * RPR;
            *(bf16x8*)&ks[row * PADQ + scg * 8] = kr[r];
            #pragma unroll
            for (int u = 0; u < 8; ++u) {
                int d = scg * 8 + u;
                vt[d * KT + ((((row >> 3) ^ (d >> 3) ^ d) & 7)) * 8 + (row & 7)] = ((short*)&vr[r])[u];
            }
        }
        __syncthreads();
        // issue next tile's global loads; latency hides under compute below
        if (k0 + KT < rows) {
            #pragma unroll
            for (int r = 0; r < NP; ++r) {
                int row = srow + r * RPR;
                kr[r] = *(const bf16x8*)&K[base + (long)(k0 + KT + row) * DM + scg * 8];
                vr[r] = *(const bf16x8*)&V[base + (long)(k0 + KT + row) * DM + scg * 8];
            }
        }
        f32x4 sc[4];
        #pragma unroll
        for (int n = 0; n < 4; ++n) {
            f32x4 c = (f32x4){0.f,0.f,0.f,0.f};
            #pragma unroll
            for (int kk = 0; kk < NKT; ++kk) {
                bf16x8 bK = *(const bf16x8*)&ks[(n * 16 + lm) * PADQ + kk * 32 + quad * 8];
                c = __builtin_amdgcn_mfma_f32_16x16x32_bf16(aQ[kk], bK, c, 0, 0, 0);
            }
            #pragma unroll
            for (int r = 0; r < 4; ++r) c[r] *= scale;
            sc[n] = c;
        }
        float alpha[4];
        #pragma unroll
        for (int r = 0; r < 4; ++r) {
            float mx = fmaxf(fmaxf(sc[0][r], sc[1][r]), fmaxf(sc[2][r], sc[3][r]));
            #pragma unroll
            for (int off = 1; off < 16; off <<= 1)
                mx = fmaxf(mx, __shfl_xor(mx, off, 64));
            float mnew = fmaxf(m4[r], mx);
            alpha[r] = __expf(m4[r] - mnew);
            m4[r] = mnew;
            float s = 0.f;
            #pragma unroll
            for (int n = 0; n < 4; ++n) {
                float p = __expf(sc[n][r] - mnew);
                sc[n][r] = p; s += p;
            }
            #pragma unroll
            for (int off = 1; off < 16; off <<= 1)
                s += __shfl_xor(s, off, 64);
            l4[r] = l4[r] * alpha[r] + s;
        }
        #pragma unroll
        for (int n = 0; n < 4; ++n)
            #pragma unroll
            for (int r = 0; r < 4; ++r)
                pP[w][(quad * 4 + r) * 72 + n * 16 + lm] = f2bf(sc[n][r]);
        #pragma unroll
        for (int d = 0; d < NDT; ++d)
            #pragma unroll
            for (int r = 0; r < 4; ++r) aco[d][r] *= alpha[r];
        #pragma unroll
        for (int d = 0; d < NDT; ++d) {
            #pragma unroll
            for (int kk = 0; kk < 2; ++kk) {
                bf16x8 aP = *(const bf16x8*)&pP[w][lm * 72 + kk * 32 + quad * 8];
                int dd = d * 16 + lm;
                int jb = kk * 4 + quad;
                bf16x8 bV = *(const bf16x8*)&vt[dd * KT + (((jb ^ (dd >> 3) ^ dd) & 7) * 8)];
                aco[d] = __builtin_amdgcn_mfma_f32_16x16x32_bf16(aP, bV, aco[d], 0, 0, 0);
            }
        }
    }
    #pragma unroll
    for (int r = 0; r < 4; ++r) l4[r] = 1.f / l4[r];
    #pragma unroll
    for (int d = 0; d < NDT; ++d)
        #pragma unroll
        for (int r = 0; r < 4; ++r)
            O[base + (long)(q0 + w * 16 + quad * 4 + r) * DM + d * 16 + lm] =
                f2bf(aco[d][r] * l4[r]);
}

// ---------------- weight transpose + fp32->bf16 -------------------------
__global__ __launch_bounds__(256) void transpose_bf16(
    const float* __restrict__ src, unsigned short* __restrict__ dst)
{
    __shared__ float tile[32][33];
    const long mb = (long)blockIdx.z * (1024l*1024l);
    const int tx = threadIdx.x & 31, ty = threadIdx.x >> 5;
    const int r0 = blockIdx.y * 32, c0 = blockIdx.x * 32;
    #pragma unroll
    for (int rr = ty; rr < 32; rr += 8)
        tile[rr][tx] = src[mb + (long)(r0+rr)*1024 + c0 + tx];
    __syncthreads();
    #pragma unroll
    for (int rr = ty; rr < 32; rr += 8)
        dst[mb + (long)(c0+rr)*1024 + r0 + tx] = f2bf(tile[tx][rr]);
}

// ---------------- flat fp32 -> bf16 convert ----------------------------
__global__ __launch_bounds__(256) void convert_bf16(
    const float* __restrict__ src, unsigned short* __restrict__ dst, long n)
{
    long i = ((long)blockIdx.x*256 + threadIdx.x)*4;
    if (i >= n) return;
    float4 v = *(const float4*)&src[i];
    ushort4 o = { f2bf(v.x), f2bf(v.y), f2bf(v.z), f2bf(v.w) };
    *(ushort4*)&dst[i] = o;
}

// ---------------- Residual + LayerNorm (fp32 out) -----------------------
__global__ __launch_bounds__(256) void ln_residual(
    const float* __restrict__ X, const float* __restrict__ R,
    const float* __restrict__ gam, const float* __restrict__ bet,
    float* __restrict__ Y)
{
    const long row = blockIdx.x;
    const int t = threadIdx.x;
    float4 xv = *(const float4*)&X[row*DM + t*4];
    float4 rv = *(const float4*)&R[row*DM + t*4];
    float v0=xv.x+rv.x, v1=xv.y+rv.y, v2=xv.z+rv.z, v3=xv.w+rv.w;
    float s  = v0+v1+v2+v3;
    float s2 = v0*v0+v1*v1+v2*v2+v3*v3;
    #pragma unroll
    for (int off = 32; off > 0; off >>= 1) {
        s  += __shfl_down(s,  off, 64);
        s2 += __shfl_down(s2, off, 64);
    }
    __shared__ float red[8];
    __shared__ float mv[2];
    const int wid = t >> 6;
    if ((t & 63) == 0) { red[wid] = s; red[4+wid] = s2; }
    __syncthreads();
    if (t == 0) {
        float S  = red[0]+red[1]+red[2]+red[3];
        float S2 = red[4]+red[5]+red[6]+red[7];
        float mean = S * (1.f/DM);
        float var  = S2 * (1.f/DM) - mean*mean;
        mv[0] = mean; mv[1] = rsqrtf(var + 1e-5f);
    }
    __syncthreads();
    float mean = mv[0], inv = mv[1];
    float4 g4 = *(const float4*)&gam[t*4];
    float4 b4 = *(const float4*)&bet[t*4];
    float4 o4;
    o4.x = (v0-mean)*inv*g4.x + b4.x;
    o4.y = (v1-mean)*inv*g4.y + b4.y;
    o4.z = (v2-mean)*inv*g4.z + b4.z;
    o4.w = (v3-mean)*inv*g4.w + b4.w;
    *(float4*)&Y[row*DM + t*4] = o4;
}

// ---------------- Combine (gather expert outs) + LN2 --------------------
__global__ __launch_bounds__(256) void combine_ln(
    const float* __restrict__ X1, const unsigned short* __restrict__ Eout,
    const int* __restrict__ e1, const int* __restrict__ pos1,
    const int* __restrict__ keep1, const float* __restrict__ g1,
    const int* __restrict__ e2, const int* __restrict__ pos2,
    const int* __restrict__ keep2, const float* __restrict__ g2,
    const float* __restrict__ gam, const float* __restrict__ bet,
    float* __restrict__ Y)
{
    const long row = blockIdx.x;
    const int b = (int)(row >> 10);
    const int t = threadIdx.x;
    float4 xv = *(const float4*)&X1[row*DM + t*4];
    float v0=xv.x, v1=xv.y, v2=xv.z, v3=xv.w;
    const float w1 = keep1[row] ? g1[row] : 0.f;
    const float w2 = keep2[row] ? g2[row] : 0.f;
    if (w1 != 0.f) {
        ushort4 u = *(const ushort4*)&Eout[(((size_t)e1[row]*BATCH + b)*CAPE + pos1[row])*DM + t*4];
        v0 += w1*bf2f(u.x); v1 += w1*bf2f(u.y); v2 += w1*bf2f(u.z); v3 += w1*bf2f(u.w);
    }
    if (w2 != 0.f) {
        ushort4 u = *(const ushort4*)&Eout[(((size_t)e2[row]*BATCH + b)*CAPE + pos2[row])*DM + t*4];
        v0 += w2*bf2f(u.x); v1 += w2*bf2f(u.y); v2 += w2*bf2f(u.z); v3 += w2*bf2f(u.w);
    }
    float s  = v0+v1+v2+v3;
    float s2 = v0*v0+v1*v1+v2*v2+v3*v3;
    #pragma unroll
    for (int off = 32; off > 0; off >>= 1) {
        s  += __shfl_down(s,  off, 64);
        s2 += __shfl_down(s2, off, 64);
    }
    __shared__ float red[8];
    __shared__ float mv[2];
    const int wid = t >> 6;
    if ((t & 63) == 0) { red[wid] = s; red[4+wid] = s2; }
    __syncthreads();
    if (t == 0) {
        float S  = red[0]+red[1]+red[2]+red[3];
        float S2 = red[4]+red[5]+red[6]+red[7];
        float mean = S * (1.f/DM);
        float var  = S2 * (1.f/DM) - mean*mean;
        mv[0] = mean; mv[1] = rsqrtf(var + 1e-5f);
    }
    __syncthreads();
    float mean = mv[0], inv = mv[1];
    float4 g4 = *(const float4*)&gam[t*4];
    float4 b4 = *(const float4*)&bet[t*4];
    float4 o4;
    o4.x = (v0-mean)*inv*g4.x + b4.x;
    o4.y = (v1-mean)*inv*g4.y + b4.y;
    o4.z = (v2-mean)*inv*g4.z + b4.z;
    o4.w = (v3-mean)*inv*g4.w + b4.w;
    *(float4*)&Y[row*DM + t*4] = o4;
}

// ---------------- Gate: 512 blocks x 4 waves, 1 wave per token ----------
__global__ __launch_bounds__(256) void gate_kernel(
    const float* __restrict__ X1, const float* __restrict__ gW,
    int* __restrict__ e1, int* __restrict__ e2,
    float* __restrict__ g1, float* __restrict__ g2,
    float* __restrict__ accum)
{
    const int t = threadIdx.x, l = t & 63, w = t >> 6;
    const int gwave = blockIdx.x * 4 + w;     // 0..2047
    float zacc = 0.f, pacc[8], facc[8];
    #pragma unroll
    for (int e = 0; e < 8; ++e) { pacc[e] = 0.f; facc[e] = 0.f; }

    for (int tok = gwave; tok < NTOK; tok += 2048) {
        const float* xr = X1 + (long)tok*DM;
        float part[8];
        #pragma unroll
        for (int e = 0; e < 8; ++e) part[e] = 0.f;
        #pragma unroll
        for (int pass = 0; pass < 4; ++pass) {
            const int i0 = pass*256 + l*4;
            float4 xv = *(const float4*)&xr[i0];
            const float xs[4] = {xv.x, xv.y, xv.z, xv.w};
            #pragma unroll
            for (int u = 0; u < 4; ++u) {
                float4 w0 = *(const float4*)&gW[(i0+u)*8];
                float4 w1 = *(const float4*)&gW[(i0+u)*8+4];
                part[0]+=xs[u]*w0.x; part[1]+=xs[u]*w0.y; part[2]+=xs[u]*w0.z; part[3]+=xs[u]*w0.w;
                part[4]+=xs[u]*w1.x; part[5]+=xs[u]*w1.y; part[6]+=xs[u]*w1.z; part[7]+=xs[u]*w1.w;
            }
        }
        #pragma unroll
        for (int e = 0; e < 8; ++e) {
            float v = part[e];
            #pragma unroll
            for (int off = 32; off > 0; off >>= 1) v += __shfl_down(v, off, 64);
            part[e] = v;
        }
        if (l == 0) {
            float mx = part[0];
            #pragma unroll
            for (int e = 1; e < 8; ++e) mx = fmaxf(mx, part[e]);
            float p[8]; float sum = 0.f;
            #pragma unroll
            for (int e = 0; e < 8; ++e) { p[e] = __expf(part[e]-mx); sum += p[e]; }
            float lse = mx + __logf(sum);
            float isum = 1.f/sum;
            #pragma unroll
            for (int e = 0; e < 8; ++e) { p[e] *= isum; pacc[e] += p[e]; }
            int b1 = 0;
            #pragma unroll
            for (int e = 1; e < 8; ++e) if (p[e] > p[b1]) b1 = e;
            int b2 = (b1 == 0) ? 1 : 0;
            #pragma unroll
            for (int e = 0; e < 8; ++e) if (e != b1 && e != b2 && p[e] > p[b2]) b2 = e;
            e1[tok] = b1; e2[tok] = b2; g1[tok] = p[b1]; g2[tok] = p[b2];
            zacc += lse*lse;
            facc[b1] += 1.f;
        }
    }
    __shared__ float red[4][17];
    if (l == 0) {
        red[w][0] = zacc;
        #pragma unroll
        for (int e = 0; e < 8; ++e) { red[w][1+e] = pacc[e]; red[w][9+e] = facc[e]; }
    }
    __syncthreads();
    if (t < 17)
        atomicAdd(&accum[t], red[0][t] + red[1][t] + red[2][t] + red[3][t]);
}

// ---------------- Routing scan ------------------------------------------
__global__ __launch_bounds__(64) void route_scan(
    const int* __restrict__ e1, const int* __restrict__ e2,
    const float* __restrict__ g2,
    int* __restrict__ pos1, int* __restrict__ keep1,
    int* __restrict__ pos2, int* __restrict__ keep2,
    int* __restrict__ slotmap)
{
    const int b = blockIdx.x;
    const int l = threadIdx.x;
    __shared__ int cnt[8];
    if (l < 8) cnt[l] = 0;
    __syncthreads();
    for (int slot = 0; slot < 2; ++slot) {
        const int* eArr = slot ? e2 : e1;
        for (int c = 0; c < SEQ/64; ++c) {
            const int tk = b*SEQ + c*64 + l;
            const int e = eArr[tk];
            const bool valid = slot ? (g2[tk] > 0.2f) : true;
            unsigned long long mymask = 0ull; int addmine = 0;
            #pragma unroll
            for (int ee = 0; ee < 8; ++ee) {
                unsigned long long bm = __ballot(valid && (e == ee));
                if (e == ee) mymask = bm;
                if (l == ee) addmine = (int)__popcll(bm);
            }
            const int p  = cnt[e] + (int)__popcll(mymask & ((1ull << l) - 1ull));
            const int kp = (valid && p < CAPE) ? 1 : 0;
            const int pc = p < CAPE ? p : (CAPE-1);
            if (slot == 0) { pos1[tk] = pc; keep1[tk] = kp; }
            else           { pos2[tk] = pc; keep2[tk] = kp; }
            if (kp) slotmap[(e*BATCH + b)*CAPE + pc] = tk;
            __syncthreads();
            if (l < 8) cnt[l] += addmine;
            __syncthreads();
        }
    }
}

// ---------------- Gather expert inputs for a 2-expert chunk -------------
__global__ __launch_bounds__(256) void gather_chunk(
    const float* __restrict__ X1, const int* __restrict__ slotmap,
    unsigned short* __restrict__ Ein, int ebase)
{
    const int slot = blockIdx.x;              // [eloc][b][p], eloc in 0..1
    const int t = threadIdx.x;
    const int tok = slotmap[ebase*(BATCH*CAPE) + slot];
    float4 v4 = make_float4(0.f, 0.f, 0.f, 0.f);
    if (tok >= 0) v4 = *(const float4*)&X1[(long)tok*DM + t*4];
    ushort4 o = { f2bf(v4.x), f2bf(v4.y), f2bf(v4.z), f2bf(v4.w) };
    *(ushort4*)&Ein[(long)slot*DM + t*4] = o;
}

// ---------------- Loss scalars ------------------------------------------
__global__ void finalize_loss(const float* __restrict__ accum, float* __restrict__ out)
{
    float z = accum[0] * (1.0f/NTOK);
    float s = 0.f;
    for (int e = 0; e < 8; ++e)
        s += (accum[1+e] * (1.0f/NTOK)) * (accum[9+e] * (1.0f/NTOK));
    float bal = 0.01f * 8.0f * s;
    float zl  = 0.001f * z;
    out[OUTN]   = bal + zl;
    out[OUTN+1] = bal;
    out[OUTN+2] = zl;
}

extern "C" void kernel_launch(void* const* d_in, const int* in_sizes, int n_in,
                              void* d_out, int out_size, void* d_ws, size_t ws_size,
                              hipStream_t stream)
{
    (void)in_sizes; (void)n_in; (void)out_size; (void)ws_size;
    const float* x    = (const float*)d_in[0];
    const float* Wq   = (const float*)d_in[1];
    const float* Wk   = (const float*)d_in[2];
    const float* Wv   = (const float*)d_in[3];
    const float* Wo   = (const float*)d_in[4];
    const float* bq   = (const float*)d_in[5];
    const float* bk   = (const float*)d_in[6];
    const float* bv   = (const float*)d_in[7];
    const float* bo   = (const float*)d_in[8];
    const float* ln1g = (const float*)d_in[9];
    const float* ln1b = (const float*)d_in[10];
    const float* ln2g = (const float*)d_in[11];
    const float* ln2b = (const float*)d_in[12];
    const float* gW   = (const float*)d_in[13];
    const float* eWq  = (const float*)d_in[14];
    const float* eWk  = (const float*)d_in[15];
    const float* eWv  = (const float*)d_in[16];
    const float* eWo  = (const float*)d_in[17];
    float* out = (float*)d_out;

    char* ws = (char*)d_ws;
    const size_t MB = 1048576;
    const long MATE = 1024l*1024l;
    // ---- layout ----
    // 0-72 MB: bf16 transposed weights
    unsigned short* WTq  = (unsigned short*)(ws);           // 3 contiguous for fused QKV
    unsigned short* WTk  = WTq + 1*MATE;
    unsigned short* WTv  = WTq + 2*MATE;
    unsigned short* WTo  = WTq + 3*MATE;
    unsigned short* eWTq = WTq + 4*MATE;
    unsigned short* eWTk = WTq + 12*MATE;
    unsigned short* eWTv = WTq + 20*MATE;
    unsigned short* eWTo = WTq + 28*MATE;
    // 72-74 MB: routing/meta
    int*   e1i   = (int*)(ws + 72*MB);
    int*   e2i   = e1i + NTOK;
    int*   pos1  = e1i + 2*NTOK;
    int*   pos2  = e1i + 3*NTOK;
    int*   keep1 = e1i + 4*NTOK;
    int*   keep2 = e1i + 5*NTOK;
    int*   slotmap = e1i + 6*NTOK;                          // 20480 ints
    float* g1f   = (float*)(e1i + 6*NTOK + NE*BATCH*CAPE);
    float* g2f   = g1f + NTOK;
    float* accum = g2f + NTOK;                              // 17 floats
    // stage-1 buffers
    unsigned short* xb = (unsigned short*)(ws + 74*MB);     // 16 MB
    unsigned short* ob = (unsigned short*)(ws + 90*MB);     // 16 MB
    unsigned short* Qb = (unsigned short*)(ws + 106*MB);    // Q/K/V contiguous 48 MB
    float* Pf = (float*)(ws + 106*MB);                      // fp32 Wo out (aliases Q/K)
    float* x1 = (float*)(ws + 154*MB);                      // 32 MB
    // expert phase (stage-1 region 74-154 dead after ln1)
    unsigned short* eoutAll = (unsigned short*)(ws + 74*MB);   // 40 MB: [8][8][320][1024]
    unsigned short* Einb = (unsigned short*)(ws + 114*MB);     // 10 MB (2-expert chunk)
    unsigned short* eqb  = (unsigned short*)(ws + 124*MB);
    unsigned short* ekb  = (unsigned short*)(ws + 134*MB);
    unsigned short* evb  = (unsigned short*)(ws + 144*MB);
    unsigned short* eob  = Einb;                               // alias (Ein dead after qkv)

    dim3 blk(256);
    dim3 tgrid(32, 32, 1), tgrid8(32, 32, 8);

    // ---- weight prep ----
    transpose_bf16<<<tgrid,  blk, 0, stream>>>(Wq,  WTq);
    transpose_bf16<<<tgrid,  blk, 0, stream>>>(Wk,  WTk);
    transpose_bf16<<<tgrid,  blk, 0, stream>>>(Wv,  WTv);
    transpose_bf16<<<tgrid,  blk, 0, stream>>>(Wo,  WTo);
    transpose_bf16<<<tgrid8, blk, 0, stream>>>(eWq, eWTq);
    transpose_bf16<<<tgrid8, blk, 0, stream>>>(eWk, eWTk);
    transpose_bf16<<<tgrid8, blk, 0, stream>>>(eWv, eWTv);
    transpose_bf16<<<tgrid8, blk, 0, stream>>>(eWo, eWTo);
    convert_bf16<<<NTOK, blk, 0, stream>>>(x, xb, OUTN);

    // ---- stage 1: MHA + LN1 ----
    gemm_qkv<<<dim3(3*DM/128, NTOK/128), blk, 0, stream>>>(xb, WTq, bq, bk, bv, Qb);
    flash_mfma<HDIM1><<<dim3(SEQ/64, NH1, BATCH), blk, 0, stream>>>(
        Qb, Qb + OUTN, Qb + 2*OUTN, ob, SEQ, 0.125f);
    gemm_bt_f32<<<dim3(DM/128, NTOK/128), blk, 0, stream>>>(ob, WTo, bo, Pf, DM, DM);
    ln_residual<<<NTOK, blk, 0, stream>>>(x, Pf, ln1g, ln1b, x1);

    // ---- gate + routing ----
    hipMemsetAsync(accum, 0, 17*sizeof(float), stream);
    hipMemsetAsync(slotmap, 0xFF, NE*BATCH*CAPE*sizeof(int), stream);
    gate_kernel<<<512, blk, 0, stream>>>(x1, gW, e1i, e2i, g1f, g2f, accum);
    route_scan<<<BATCH, dim3(64), 0, stream>>>(e1i, e2i, g2f, pos1, keep1, pos2, keep2, slotmap);

    // ---- experts: 4 chunks of 2 ----
    for (int c = 0; c < 4; ++c) {
        const int ebase = c*2;
        gather_chunk<<<2*BATCH*CAPE, blk, 0, stream>>>(x1, slotmap, Einb, ebase);
        gemm_eqkv<<<dim3(DM/128, 2*BATCH*CAPE/128, 3), blk, 0, stream>>>(
            Einb, eWTq, eWTk, eWTv, eqb, ekb, evb, ebase);
        flash_mfma<HDIM2><<<dim3(CAPE/64, NH2, 2*BATCH), blk, 0, stream>>>(
            eqb, ekb, evb, eob, CAPE, 0.088388347648318447f);
        gemm_eout<<<dim3(DM/128, 2*BATCH*CAPE/128), blk, 0, stream>>>(
            eob, eWTo, eoutAll + (size_t)ebase*ECB, ebase);
    }

    // ---- combine + final LN + losses ----
    combine_ln<<<NTOK, blk, 0, stream>>>(x1, eoutAll, e1i, pos1, keep1, g1f,
                                         e2i, pos2, keep2, g2f, ln2g, ln2b, out);
    finalize_loss<<<1, 1, 0, stream>>>(accum, out);
}

// Round 5
// 1026.768 us; speedup vs baseline: 1.1266x; 1.0032x over previous
//
#include <hip/hip_runtime.h>
#include <hip/hip_bf16.h>
#include <math.h>

#define DM    1024
#define NH1   16
#define HDIM1 64
#define NH2   8
#define HDIM2 128
#define NE    8
#define CAPE  320
#define BATCH 8
#define SEQ   1024
#define NTOK  (BATCH*SEQ)        /* 8192 */
#define OUTN  ((long)NTOK*DM)    /* 8388608 */
#define ECB   ((long)BATCH*CAPE*DM)  /* 2,621,440 elems per expert */

typedef short bf16x8 __attribute__((ext_vector_type(8)));
typedef float f32x4  __attribute__((ext_vector_type(4)));

__device__ __forceinline__ unsigned short f2bf(float f) {
    __hip_bfloat16 h = __float2bfloat16(f);
    return *reinterpret_cast<unsigned short*>(&h);
}
__device__ __forceinline__ float bf2f(unsigned short u) {
    unsigned int x = ((unsigned int)u) << 16;
    return __builtin_bit_cast(float, x);
}

__device__ __forceinline__ void async16(const void* g, void* lds) {
    __builtin_amdgcn_global_load_lds(
        (const __attribute__((address_space(1))) unsigned int*)g,
        (__attribute__((address_space(3))) unsigned int*)lds, 16, 0, 0);
}

// ---------------- shared GEMM core: 128x128 tile, BK=32, 4 waves --------
// acc[i][j] accumulates C-tile (wr,wc wave grid). A[M,K], Bt[N,K] bf16.
__device__ __forceinline__ void gemm_core(
    const unsigned short* __restrict__ A, const unsigned short* __restrict__ Bt,
    int m0, int n0, int K, short* ldsA, short* ldsB, f32x4 (&acc)[4][4])
{
    const int t    = threadIdx.x;
    const int lane = t & 63, w = t >> 6;
    const int wr = w >> 1, wc = w & 1;
    const int lq = lane >> 4, lm = lane & 15;
    const int srow = w*16 + (lane >> 2);
    const int skc  = (lane & 3) * 8;
    for (int kb = 0; kb < K; kb += 32) {
        #pragma unroll
        for (int p = 0; p < 2; ++p) {
            async16(A  + (size_t)(m0 + srow + p*64)*K + kb + skc,
                    &ldsA[(w*16 + p*64)*32]);
            async16(Bt + (size_t)(n0 + srow + p*64)*K + kb + skc,
                    &ldsB[(w*16 + p*64)*32]);
        }
        __syncthreads();
        bf16x8 aF[4], bF[4];
        #pragma unroll
        for (int i = 0; i < 4; ++i)
            aF[i] = *(const bf16x8*)&ldsA[(wr*64 + i*16 + lm)*32 + lq*8];
        #pragma unroll
        for (int j = 0; j < 4; ++j)
            bF[j] = *(const bf16x8*)&ldsB[(wc*64 + j*16 + lm)*32 + lq*8];
        #pragma unroll
        for (int i = 0; i < 4; ++i)
            #pragma unroll
            for (int j = 0; j < 4; ++j)
                acc[i][j] = __builtin_amdgcn_mfma_f32_16x16x32_bf16(aF[i], bF[j], acc[i][j], 0, 0, 0);
        __syncthreads();
    }
}

// ---------------- plain GEMM (fp32 out, bias) — used for Wo projection ----
__global__ __launch_bounds__(256) void gemm_bt_f32(
    const unsigned short* __restrict__ A, const unsigned short* __restrict__ Bt,
    const float* __restrict__ bias, float* __restrict__ C, int N, int K)
{
    __shared__ short ldsA[128*32];
    __shared__ short ldsB[128*32];
    const int lane = threadIdx.x & 63, w = threadIdx.x >> 6;
    const int wr = w >> 1, wc = w & 1;
    const int lq = lane >> 4, lm = lane & 15;
    const int m0 = blockIdx.y * 128, n0 = blockIdx.x * 128;
    f32x4 acc[4][4];
    #pragma unroll
    for (int i = 0; i < 4; ++i)
        #pragma unroll
        for (int j = 0; j < 4; ++j) acc[i][j] = (f32x4){0.f,0.f,0.f,0.f};
    gemm_core(A, Bt, m0, n0, K, ldsA, ldsB, acc);
    #pragma unroll
    for (int j = 0; j < 4; ++j) {
        const int gcol = n0 + wc*64 + j*16 + lm;
        const float badd = bias ? bias[gcol] : 0.f;
        #pragma unroll
        for (int i = 0; i < 4; ++i) {
            const int grow = m0 + wr*64 + i*16 + lq*4;
            #pragma unroll
            for (int r = 0; r < 4; ++r)
                C[(size_t)(grow + r)*N + gcol] = acc[i][j][r] + badd;
        }
    }
}

// ---------------- fused main QKV GEMM: Bt = [WTq;WTk;WTv] (3072 x 1024) ----
// C base = Qb; Q/K/V outputs contiguous, each OUTN elems. bf16 out.
__global__ __launch_bounds__(256) void gemm_qkv(
    const unsigned short* __restrict__ A, const unsigned short* __restrict__ Bt,
    const float* __restrict__ bq, const float* __restrict__ bk, const float* __restrict__ bv,
    unsigned short* __restrict__ C)
{
    __shared__ short ldsA[128*32];
    __shared__ short ldsB[128*32];
    const int lane = threadIdx.x & 63, w = threadIdx.x >> 6;
    const int wr = w >> 1, wc = w & 1;
    const int lq = lane >> 4, lm = lane & 15;
    const int m0 = blockIdx.y * 128, n0g = blockIdx.x * 128;
    const int buf = n0g >> 10;
    const float* bias = (buf == 0) ? bq : (buf == 1) ? bk : bv;
    unsigned short* Cb = C + (size_t)buf * OUTN;
    f32x4 acc[4][4];
    #pragma unroll
    for (int i = 0; i < 4; ++i)
        #pragma unroll
        for (int j = 0; j < 4; ++j) acc[i][j] = (f32x4){0.f,0.f,0.f,0.f};
    gemm_core(A, Bt, m0, n0g, DM, ldsA, ldsB, acc);
    #pragma unroll
    for (int j = 0; j < 4; ++j) {
        const int gcol = (n0g & 1023) + wc*64 + j*16 + lm;
        const float badd = bias[gcol];
        #pragma unroll
        for (int i = 0; i < 4; ++i) {
            const int grow = m0 + wr*64 + i*16 + lq*4;
            #pragma unroll
            for (int r = 0; r < 4; ++r)
                Cb[(size_t)(grow + r)*DM + gcol] = f2bf(acc[i][j][r] + badd);
        }
    }
}

// ---------------- grouped expert QKV GEMM (2 experts per chunk) ----------
// grid (8, 40, 3): z selects {q,k,v}; y-block / 20 selects expert-in-chunk.
__global__ __launch_bounds__(256) void gemm_eqkv(
    const unsigned short* __restrict__ A,
    const unsigned short* __restrict__ eWTq, const unsigned short* __restrict__ eWTk,
    const unsigned short* __restrict__ eWTv,
    unsigned short* __restrict__ Cq, unsigned short* __restrict__ Ck,
    unsigned short* __restrict__ Cv, int ebase)
{
    __shared__ short ldsA[128*32];
    __shared__ short ldsB[128*32];
    const int lane = threadIdx.x & 63, w = threadIdx.x >> 6;
    const int wr = w >> 1, wc = w & 1;
    const int lq = lane >> 4, lm = lane & 15;
    const int z = blockIdx.z;
    const int eloc = blockIdx.y / 20;
    const unsigned short* Bt =
        ((z == 0) ? eWTq : (z == 1) ? eWTk : eWTv) + (size_t)(ebase + eloc) * (1024l*1024l);
    unsigned short* C = (z == 0) ? Cq : (z == 1) ? Ck : Cv;
    const int m0 = blockIdx.y * 128, n0 = blockIdx.x * 128;
    f32x4 acc[4][4];
    #pragma unroll
    for (int i = 0; i < 4; ++i)
        #pragma unroll
        for (int j = 0; j < 4; ++j) acc[i][j] = (f32x4){0.f,0.f,0.f,0.f};
    gemm_core(A, Bt, m0, n0, DM, ldsA, ldsB, acc);
    #pragma unroll
    for (int j = 0; j < 4; ++j) {
        const int gcol = n0 + wc*64 + j*16 + lm;
        #pragma unroll
        for (int i = 0; i < 4; ++i) {
            const int grow = m0 + wr*64 + i*16 + lq*4;
            #pragma unroll
            for (int r = 0; r < 4; ++r)
                C[(size_t)(grow + r)*DM + gcol] = f2bf(acc[i][j][r]);
        }
    }
}

// ---------------- grouped expert output GEMM (bf16 out) ------------------
__global__ __launch_bounds__(256) void gemm_eout(
    const unsigned short* __restrict__ A, const unsigned short* __restrict__ eWTo,
    unsigned short* __restrict__ C, int ebase)
{
    __shared__ short ldsA[128*32];
    __shared__ short ldsB[128*32];
    const int lane = threadIdx.x & 63, w = threadIdx.x >> 6;
    const int wr = w >> 1, wc = w & 1;
    const int lq = lane >> 4, lm = lane & 15;
    const int eloc = blockIdx.y / 20;
    const unsigned short* Bt = eWTo + (size_t)(ebase + eloc) * (1024l*1024l);
    const int m0 = blockIdx.y * 128, n0 = blockIdx.x * 128;
    f32x4 acc[4][4];
    #pragma unroll
    for (int i = 0; i < 4; ++i)
        #pragma unroll
        for (int j = 0; j < 4; ++j) acc[i][j] = (f32x4){0.f,0.f,0.f,0.f};
    gemm_core(A, Bt, m0, n0, DM, ldsA, ldsB, acc);
    #pragma unroll
    for (int j = 0; j < 4; ++j) {
        const int gcol = n0 + wc*64 + j*16 + lm;
        #pragma unroll
        for (int i = 0; i < 4; ++i) {
            const int grow = m0 + wr*64 + i*16 + lq*4;
            #pragma unroll
            for (int r = 0; r < 4; ++r)
                C[(size_t)(grow + r)*DM + gcol] = f2bf(acc[i][j][r]);
        }
    }
}

// ---------------- MFMA flash attention (bf16 in/out, fp32 softmax) ------
// NS = Q-strips per block (QT = 64*NS). Strip-mining amortizes the K/V
// staging (global loads + V-transpose scatter + barriers) over 2x the
// output rows and halves K/V HBM re-reads. Per-strip state aQ/m4/l4/aco
// is statically indexed (full unroll). pP row stride 76 (72 made quads
// 0/2,1/3 collide -> 4-way conflict on P stores; 76 -> quad bank offsets
// {0,24,16,8}, conflict-free). V-transpose swizzle ((k>>3)^(d>>3)^d)&7
// on both sides (conflict fix from R1). Plain __launch_bounds__(256):
// the (256,4)/(256,3) pins were the only untested delta in the two
// failed submissions; compiler's natural VGPR choice avoids forced spill.
template<int HD, int NS>
__global__ __launch_bounds__(256) void flash_mfma(
    const unsigned short* __restrict__ Q, const unsigned short* __restrict__ K,
    const unsigned short* __restrict__ V, unsigned short* __restrict__ O,
    int rows, float scale)
{
    constexpr int KT = 64;
    constexpr int PADQ = HD + 8;
    constexpr int NKT = HD / 32;
    constexpr int NDT = HD / 16;
    constexpr int CG  = HD / 8;
    constexpr int RPR = 256 / CG;
    constexpr int NP  = KT / RPR;      // K/V rows per thread per tile
    constexpr int PST = 76;            // pP row stride in shorts
    __shared__ __align__(16) unsigned short ks[KT * PADQ];
    __shared__ __align__(16) unsigned short vt[HD * KT];
    __shared__ __align__(16) unsigned short pP[4][16 * PST];
    const int t = threadIdx.x, lane = t & 63, w = t >> 6;
    const int lm = lane & 15, quad = lane >> 4;
    const int q0 = blockIdx.x * (64 * NS);
    const long base = (long)blockIdx.z * rows * DM + (long)blockIdx.y * HD;
    const int srow = t / CG, scg = t % CG;

    // ---- stage Q strip-by-strip through ks, consume into registers ----
    bf16x8 aQ[NS][NKT];
    #pragma unroll
    for (int s = 0; s < NS; ++s) {
        if (s) __syncthreads();
        #pragma unroll
        for (int r = 0; r < 64 / RPR; ++r) {
            int row = srow + r * RPR;
            *(bf16x8*)&ks[row * PADQ + scg * 8] =
                *(const bf16x8*)&Q[base + (long)(q0 + s * 64 + row) * DM + scg * 8];
        }
        __syncthreads();
        #pragma unroll
        for (int kk = 0; kk < NKT; ++kk)
            aQ[s][kk] = *(const bf16x8*)&ks[(w * 16 + lm) * PADQ + kk * 32 + quad * 8];
    }

    float m4[NS][4], l4[NS][4];
    f32x4 aco[NS][NDT];
    #pragma unroll
    for (int s = 0; s < NS; ++s) {
        #pragma unroll
        for (int r = 0; r < 4; ++r) { m4[s][r] = -1e30f; l4[s][r] = 0.f; }
        #pragma unroll
        for (int d = 0; d < NDT; ++d) aco[s][d] = (f32x4){0.f,0.f,0.f,0.f};
    }

    // ---- preload K/V tile 0 into registers (T14 async split) ----
    bf16x8 kr[NP], vr[NP];
    #pragma unroll
    for (int r = 0; r < NP; ++r) {
        int row = srow + r * RPR;
        kr[r] = *(const bf16x8*)&K[base + (long)row * DM + scg * 8];
        vr[r] = *(const bf16x8*)&V[base + (long)row * DM + scg * 8];
    }

    for (int k0 = 0; k0 < rows; k0 += KT) {
        __syncthreads();   // prev compute done with ks/vt (iter 0: aQ reads drained)
        #pragma unroll
        for (int r = 0; r < NP; ++r) {
            int row = srow + r * RPR;
            *(bf16x8*)&ks[row * PADQ + scg * 8] = kr[r];
            #pragma unroll
            for (int u = 0; u < 8; ++u) {
                int d = scg * 8 + u;
                vt[d * KT + ((((row >> 3) ^ (d >> 3) ^ d) & 7)) * 8 + (row & 7)] = ((short*)&vr[r])[u];
            }
        }
        __syncthreads();
        // issue next tile's global loads; latency hides under compute below
        if (k0 + KT < rows) {
            #pragma unroll
            for (int r = 0; r < NP; ++r) {
                int row = srow + r * RPR;
                kr[r] = *(const bf16x8*)&K[base + (long)(k0 + KT + row) * DM + scg * 8];
                vr[r] = *(const bf16x8*)&V[base + (long)(k0 + KT + row) * DM + scg * 8];
            }
        }
        #pragma unroll
        for (int s = 0; s < NS; ++s) {
            f32x4 sc[4];
            #pragma unroll
            for (int n = 0; n < 4; ++n) {
                f32x4 c = (f32x4){0.f,0.f,0.f,0.f};
                #pragma unroll
                for (int kk = 0; kk < NKT; ++kk) {
                    bf16x8 bK = *(const bf16x8*)&ks[(n * 16 + lm) * PADQ + kk * 32 + quad * 8];
                    c = __builtin_amdgcn_mfma_f32_16x16x32_bf16(aQ[s][kk], bK, c, 0, 0, 0);
                }
                #pragma unroll
                for (int r = 0; r < 4; ++r) c[r] *= scale;
                sc[n] = c;
            }
            float alpha[4];
            #pragma unroll
            for (int r = 0; r < 4; ++r) {
                float mx = fmaxf(fmaxf(sc[0][r], sc[1][r]), fmaxf(sc[2][r], sc[3][r]));
                #pragma unroll
                for (int off = 1; off < 16; off <<= 1)
                    mx = fmaxf(mx, __shfl_xor(mx, off, 64));
                float mnew = fmaxf(m4[s][r], mx);
                alpha[r] = __expf(m4[s][r] - mnew);
                m4[s][r] = mnew;
                float sum = 0.f;
                #pragma unroll
                for (int n = 0; n < 4; ++n) {
                    float p = __expf(sc[n][r] - mnew);
                    sc[n][r] = p; sum += p;
                }
                #pragma unroll
                for (int off = 1; off < 16; off <<= 1)
                    sum += __shfl_xor(sum, off, 64);
                l4[s][r] = l4[s][r] * alpha[r] + sum;
            }
            #pragma unroll
            for (int n = 0; n < 4; ++n)
                #pragma unroll
                for (int r = 0; r < 4; ++r)
                    pP[w][(quad * 4 + r) * PST + n * 16 + lm] = f2bf(sc[n][r]);
            #pragma unroll
            for (int d = 0; d < NDT; ++d)
                #pragma unroll
                for (int r = 0; r < 4; ++r) aco[s][d][r] *= alpha[r];
            #pragma unroll
            for (int d = 0; d < NDT; ++d) {
                #pragma unroll
                for (int kk = 0; kk < 2; ++kk) {
                    bf16x8 aP = *(const bf16x8*)&pP[w][lm * PST + kk * 32 + quad * 8];
                    int dd = d * 16 + lm;
                    int jb = kk * 4 + quad;
                    bf16x8 bV = *(const bf16x8*)&vt[dd * KT + (((jb ^ (dd >> 3) ^ dd) & 7) * 8)];
                    aco[s][d] = __builtin_amdgcn_mfma_f32_16x16x32_bf16(aP, bV, aco[s][d], 0, 0, 0);
                }
            }
        }
    }
    #pragma unroll
    for (int s = 0; s < NS; ++s)
        #pragma unroll
        for (int r = 0; r < 4; ++r) {
            float inv = 1.f / l4[s][r];
            #pragma unroll
            for (int d = 0; d < NDT; ++d)
                O[base + (long)(q0 + s * 64 + w * 16 + quad * 4 + r) * DM + d * 16 + lm] =
                    f2bf(aco[s][d][r] * inv);
        }
}

// ---------------- weight transpose + fp32->bf16 -------------------------
__global__ __launch_bounds__(256) void transpose_bf16(
    const float* __restrict__ src, unsigned short* __restrict__ dst)
{
    __shared__ float tile[32][33];
    const long mb = (long)blockIdx.z * (1024l*1024l);
    const int tx = threadIdx.x & 31, ty = threadIdx.x >> 5;
    const int r0 = blockIdx.y * 32, c0 = blockIdx.x * 32;
    #pragma unroll
    for (int rr = ty; rr < 32; rr += 8)
        tile[rr][tx] = src[mb + (long)(r0+rr)*1024 + c0 + tx];
    __syncthreads();
    #pragma unroll
    for (int rr = ty; rr < 32; rr += 8)
        dst[mb + (long)(c0+rr)*1024 + r0 + tx] = f2bf(tile[tx][rr]);
}

// ---------------- flat fp32 -> bf16 convert ----------------------------
__global__ __launch_bounds__(256) void convert_bf16(
    const float* __restrict__ src, unsigned short* __restrict__ dst, long n)
{
    long i = ((long)blockIdx.x*256 + threadIdx.x)*4;
    if (i >= n) return;
    float4 v = *(const float4*)&src[i];
    ushort4 o = { f2bf(v.x), f2bf(v.y), f2bf(v.z), f2bf(v.w) };
    *(ushort4*)&dst[i] = o;
}

// ---------------- Residual + LayerNorm (fp32 out) -----------------------
__global__ __launch_bounds__(256) void ln_residual(
    const float* __restrict__ X, const float* __restrict__ R,
    const float* __restrict__ gam, const float* __restrict__ bet,
    float* __restrict__ Y)
{
    const long row = blockIdx.x;
    const int t = threadIdx.x;
    float4 xv = *(const float4*)&X[row*DM + t*4];
    float4 rv = *(const float4*)&R[row*DM + t*4];
    float v0=xv.x+rv.x, v1=xv.y+rv.y, v2=xv.z+rv.z, v3=xv.w+rv.w;
    float s  = v0+v1+v2+v3;
    float s2 = v0*v0+v1*v1+v2*v2+v3*v3;
    #pragma unroll
    for (int off = 32; off > 0; off >>= 1) {
        s  += __shfl_down(s,  off, 64);
        s2 += __shfl_down(s2, off, 64);
    }
    __shared__ float red[8];
    __shared__ float mv[2];
    const int wid = t >> 6;
    if ((t & 63) == 0) { red[wid] = s; red[4+wid] = s2; }
    __syncthreads();
    if (t == 0) {
        float S  = red[0]+red[1]+red[2]+red[3];
        float S2 = red[4]+red[5]+red[6]+red[7];
        float mean = S * (1.f/DM);
        float var  = S2 * (1.f/DM) - mean*mean;
        mv[0] = mean; mv[1] = rsqrtf(var + 1e-5f);
    }
    __syncthreads();
    float mean = mv[0], inv = mv[1];
    float4 g4 = *(const float4*)&gam[t*4];
    float4 b4 = *(const float4*)&bet[t*4];
    float4 o4;
    o4.x = (v0-mean)*inv*g4.x + b4.x;
    o4.y = (v1-mean)*inv*g4.y + b4.y;
    o4.z = (v2-mean)*inv*g4.z + b4.z;
    o4.w = (v3-mean)*inv*g4.w + b4.w;
    *(float4*)&Y[row*DM + t*4] = o4;
}

// ---------------- Combine (gather expert outs) + LN2 --------------------
__global__ __launch_bounds__(256) void combine_ln(
    const float* __restrict__ X1, const unsigned short* __restrict__ Eout,
    const int* __restrict__ e1, const int* __restrict__ pos1,
    const int* __restrict__ keep1, const float* __restrict__ g1,
    const int* __restrict__ e2, const int* __restrict__ pos2,
    const int* __restrict__ keep2, const float* __restrict__ g2,
    const float* __restrict__ gam, const float* __restrict__ bet,
    float* __restrict__ Y)
{
    const long row = blockIdx.x;
    const int b = (int)(row >> 10);
    const int t = threadIdx.x;
    float4 xv = *(const float4*)&X1[row*DM + t*4];
    float v0=xv.x, v1=xv.y, v2=xv.z, v3=xv.w;
    const float w1 = keep1[row] ? g1[row] : 0.f;
    const float w2 = keep2[row] ? g2[row] : 0.f;
    if (w1 != 0.f) {
        ushort4 u = *(const ushort4*)&Eout[(((size_t)e1[row]*BATCH + b)*CAPE + pos1[row])*DM + t*4];
        v0 += w1*bf2f(u.x); v1 += w1*bf2f(u.y); v2 += w1*bf2f(u.z); v3 += w1*bf2f(u.w);
    }
    if (w2 != 0.f) {
        ushort4 u = *(const ushort4*)&Eout[(((size_t)e2[row]*BATCH + b)*CAPE + pos2[row])*DM + t*4];
        v0 += w2*bf2f(u.x); v1 += w2*bf2f(u.y); v2 += w2*bf2f(u.z); v3 += w2*bf2f(u.w);
    }
    float s  = v0+v1+v2+v3;
    float s2 = v0*v0+v1*v1+v2*v2+v3*v3;
    #pragma unroll
    for (int off = 32; off > 0; off >>= 1) {
        s  += __shfl_down(s,  off, 64);
        s2 += __shfl_down(s2, off, 64);
    }
    __shared__ float red[8];
    __shared__ float mv[2];
    const int wid = t >> 6;
    if ((t & 63) == 0) { red[wid] = s; red[4+wid] = s2; }
    __syncthreads();
    if (t == 0) {
        float S  = red[0]+red[1]+red[2]+red[3];
        float S2 = red[4]+red[5]+red[6]+red[7];
        float mean = S * (1.f/DM);
        float var  = S2 * (1.f/DM) - mean*mean;
        mv[0] = mean; mv[1] = rsqrtf(var + 1e-5f);
    }
    __syncthreads();
    float mean = mv[0], inv = mv[1];
    float4 g4 = *(const float4*)&gam[t*4];
    float4 b4 = *(const float4*)&bet[t*4];
    float4 o4;
    o4.x = (v0-mean)*inv*g4.x + b4.x;
    o4.y = (v1-mean)*inv*g4.y + b4.y;
    o4.z = (v2-mean)*inv*g4.z + b4.z;
    o4.w = (v3-mean)*inv*g4.w + b4.w;
    *(float4*)&Y[row*DM + t*4] = o4;
}

// ---------------- Gate: 512 blocks x 4 waves, 1 wave per token ----------
__global__ __launch_bounds__(256) void gate_kernel(
    const float* __restrict__ X1, const float* __restrict__ gW,
    int* __restrict__ e1, int* __restrict__ e2,
    float* __restrict__ g1, float* __restrict__ g2,
    float* __restrict__ accum)
{
    const int t = threadIdx.x, l = t & 63, w = t >> 6;
    const int gwave = blockIdx.x * 4 + w;     // 0..2047
    float zacc = 0.f, pacc[8], facc[8];
    #pragma unroll
    for (int e = 0; e < 8; ++e) { pacc[e] = 0.f; facc[e] = 0.f; }

    for (int tok = gwave; tok < NTOK; tok += 2048) {
        const float* xr = X1 + (long)tok*DM;
        float part[8];
        #pragma unroll
        for (int e = 0; e < 8; ++e) part[e] = 0.f;
        #pragma unroll
        for (int pass = 0; pass < 4; ++pass) {
            const int i0 = pass*256 + l*4;
            float4 xv = *(const float4*)&xr[i0];
            const float xs[4] = {xv.x, xv.y, xv.z, xv.w};
            #pragma unroll
            for (int u = 0; u < 4; ++u) {
                float4 w0 = *(const float4*)&gW[(i0+u)*8];
                float4 w1 = *(const float4*)&gW[(i0+u)*8+4];
                part[0]+=xs[u]*w0.x; part[1]+=xs[u]*w0.y; part[2]+=xs[u]*w0.z; part[3]+=xs[u]*w0.w;
                part[4]+=xs[u]*w1.x; part[5]+=xs[u]*w1.y; part[6]+=xs[u]*w1.z; part[7]+=xs[u]*w1.w;
            }
        }
        #pragma unroll
        for (int e = 0; e < 8; ++e) {
            float v = part[e];
            #pragma unroll
            for (int off = 32; off > 0; off >>= 1) v += __shfl_down(v, off, 64);
            part[e] = v;
        }
        if (l == 0) {
            float mx = part[0];
            #pragma unroll
            for (int e = 1; e < 8; ++e) mx = fmaxf(mx, part[e]);
            float p[8]; float sum = 0.f;
            #pragma unroll
            for (int e = 0; e < 8; ++e) { p[e] = __expf(part[e]-mx); sum += p[e]; }
            float lse = mx + __logf(sum);
            float isum = 1.f/sum;
            #pragma unroll
            for (int e = 0; e < 8; ++e) { p[e] *= isum; pacc[e] += p[e]; }
            int b1 = 0;
            #pragma unroll
            for (int e = 1; e < 8; ++e) if (p[e] > p[b1]) b1 = e;
            int b2 = (b1 == 0) ? 1 : 0;
            #pragma unroll
            for (int e = 0; e < 8; ++e) if (e != b1 && e != b2 && p[e] > p[b2]) b2 = e;
            e1[tok] = b1; e2[tok] = b2; g1[tok] = p[b1]; g2[tok] = p[b2];
            zacc += lse*lse;
            facc[b1] += 1.f;
        }
    }
    __shared__ float red[4][17];
    if (l == 0) {
        red[w][0] = zacc;
        #pragma unroll
        for (int e = 0; e < 8; ++e) { red[w][1+e] = pacc[e]; red[w][9+e] = facc[e]; }
    }
    __syncthreads();
    if (t < 17)
        atomicAdd(&accum[t], red[0][t] + red[1][t] + red[2][t] + red[3][t]);
}

// ---------------- Routing scan ------------------------------------------
__global__ __launch_bounds__(64) void route_scan(
    const int* __restrict__ e1, const int* __restrict__ e2,
    const float* __restrict__ g2,
    int* __restrict__ pos1, int* __restrict__ keep1,
    int* __restrict__ pos2, int* __restrict__ keep2,
    int* __restrict__ slotmap)
{
    const int b = blockIdx.x;
    const int l = threadIdx.x;
    __shared__ int cnt[8];
    if (l < 8) cnt[l] = 0;
    __syncthreads();
    for (int slot = 0; slot < 2; ++slot) {
        const int* eArr = slot ? e2 : e1;
        for (int c = 0; c < SEQ/64; ++c) {
            const int tk = b*SEQ + c*64 + l;
            const int e = eArr[tk];
            const bool valid = slot ? (g2[tk] > 0.2f) : true;
            unsigned long long mymask = 0ull; int addmine = 0;
            #pragma unroll
            for (int ee = 0; ee < 8; ++ee) {
                unsigned long long bm = __ballot(valid && (e == ee));
                if (e == ee) mymask = bm;
                if (l == ee) addmine = (int)__popcll(bm);
            }
            const int p  = cnt[e] + (int)__popcll(mymask & ((1ull << l) - 1ull));
            const int kp = (valid && p < CAPE) ? 1 : 0;
            const int pc = p < CAPE ? p : (CAPE-1);
            if (slot == 0) { pos1[tk] = pc; keep1[tk] = kp; }
            else           { pos2[tk] = pc; keep2[tk] = kp; }
            if (kp) slotmap[(e*BATCH + b)*CAPE + pc] = tk;
            __syncthreads();
            if (l < 8) cnt[l] += addmine;
            __syncthreads();
        }
    }
}

// ---------------- Gather expert inputs for a 2-expert chunk -------------
__global__ __launch_bounds__(256) void gather_chunk(
    const float* __restrict__ X1, const int* __restrict__ slotmap,
    unsigned short* __restrict__ Ein, int ebase)
{
    const int slot = blockIdx.x;              // [eloc][b][p], eloc in 0..1
    const int t = threadIdx.x;
    const int tok = slotmap[ebase*(BATCH*CAPE) + slot];
    float4 v4 = make_float4(0.f, 0.f, 0.f, 0.f);
    if (tok >= 0) v4 = *(const float4*)&X1[(long)tok*DM + t*4];
    ushort4 o = { f2bf(v4.x), f2bf(v4.y), f2bf(v4.z), f2bf(v4.w) };
    *(ushort4*)&Ein[(long)slot*DM + t*4] = o;
}

// ---------------- Loss scalars ------------------------------------------
__global__ void finalize_loss(const float* __restrict__ accum, float* __restrict__ out)
{
    float z = accum[0] * (1.0f/NTOK);
    float s = 0.f;
    for (int e = 0; e < 8; ++e)
        s += (accum[1+e] * (1.0f/NTOK)) * (accum[9+e] * (1.0f/NTOK));
    float bal = 0.01f * 8.0f * s;
    float zl  = 0.001f * z;
    out[OUTN]   = bal + zl;
    out[OUTN+1] = bal;
    out[OUTN+2] = zl;
}

extern "C" void kernel_launch(void* const* d_in, const int* in_sizes, int n_in,
                              void* d_out, int out_size, void* d_ws, size_t ws_size,
                              hipStream_t stream)
{
    (void)in_sizes; (void)n_in; (void)out_size; (void)ws_size;
    const float* x    = (const float*)d_in[0];
    const float* Wq   = (const float*)d_in[1];
    const float* Wk   = (const float*)d_in[2];
    const float* Wv   = (const float*)d_in[3];
    const float* Wo   = (const float*)d_in[4];
    const float* bq   = (const float*)d_in[5];
    const float* bk   = (const float*)d_in[6];
    const float* bv   = (const float*)d_in[7];
    const float* bo   = (const float*)d_in[8];
    const float* ln1g = (const float*)d_in[9];
    const float* ln1b = (const float*)d_in[10];
    const float* ln2g = (const float*)d_in[11];
    const float* ln2b = (const float*)d_in[12];
    const float* gW   = (const float*)d_in[13];
    const float* eWq  = (const float*)d_in[14];
    const float* eWk  = (const float*)d_in[15];
    const float* eWv  = (const float*)d_in[16];
    const float* eWo  = (const float*)d_in[17];
    float* out = (float*)d_out;

    char* ws = (char*)d_ws;
    const size_t MB = 1048576;
    const long MATE = 1024l*1024l;
    // ---- layout ----
    // 0-72 MB: bf16 transposed weights
    unsigned short* WTq  = (unsigned short*)(ws);           // 3 contiguous for fused QKV
    unsigned short* WTk  = WTq + 1*MATE;
    unsigned short* WTv  = WTq + 2*MATE;
    unsigned short* WTo  = WTq + 3*MATE;
    unsigned short* eWTq = WTq + 4*MATE;
    unsigned short* eWTk = WTq + 12*MATE;
    unsigned short* eWTv = WTq + 20*MATE;
    unsigned short* eWTo = WTq + 28*MATE;
    // 72-74 MB: routing/meta
    int*   e1i   = (int*)(ws + 72*MB);
    int*   e2i   = e1i + NTOK;
    int*   pos1  = e1i + 2*NTOK;
    int*   pos2  = e1i + 3*NTOK;
    int*   keep1 = e1i + 4*NTOK;
    int*   keep2 = e1i + 5*NTOK;
    int*   slotmap = e1i + 6*NTOK;                          // 20480 ints
    float* g1f   = (float*)(e1i + 6*NTOK + NE*BATCH*CAPE);
    float* g2f   = g1f + NTOK;
    float* accum = g2f + NTOK;                              // 17 floats
    // stage-1 buffers
    unsigned short* xb = (unsigned short*)(ws + 74*MB);     // 16 MB
    unsigned short* ob = (unsigned short*)(ws + 90*MB);     // 16 MB
    unsigned short* Qb = (unsigned short*)(ws + 106*MB);    // Q/K/V contiguous 48 MB
    float* Pf = (float*)(ws + 106*MB);                      // fp32 Wo out (aliases Q/K)
    float* x1 = (float*)(ws + 154*MB);                      // 32 MB
    // expert phase (stage-1 region 74-154 dead after ln1)
    unsigned short* eoutAll = (unsigned short*)(ws + 74*MB);   // 40 MB: [8][8][320][1024]
    unsigned short* Einb = (unsigned short*)(ws + 114*MB);     // 10 MB (2-expert chunk)
    unsigned short* eqb  = (unsigned short*)(ws + 124*MB);
    unsigned short* ekb  = (unsigned short*)(ws + 134*MB);
    unsigned short* evb  = (unsigned short*)(ws + 144*MB);
    unsigned short* eob  = Einb;                               // alias (Ein dead after qkv)

    dim3 blk(256);
    dim3 tgrid(32, 32, 1), tgrid8(32, 32, 8);

    // ---- weight prep ----
    transpose_bf16<<<tgrid,  blk, 0, stream>>>(Wq,  WTq);
    transpose_bf16<<<tgrid,  blk, 0, stream>>>(Wk,  WTk);
    transpose_bf16<<<tgrid,  blk, 0, stream>>>(Wv,  WTv);
    transpose_bf16<<<tgrid,  blk, 0, stream>>>(Wo,  WTo);
    transpose_bf16<<<tgrid8, blk, 0, stream>>>(eWq, eWTq);
    transpose_bf16<<<tgrid8, blk, 0, stream>>>(eWk, eWTk);
    transpose_bf16<<<tgrid8, blk, 0, stream>>>(eWv, eWTv);
    transpose_bf16<<<tgrid8, blk, 0, stream>>>(eWo, eWTo);
    convert_bf16<<<NTOK, blk, 0, stream>>>(x, xb, OUTN);

    // ---- stage 1: MHA + LN1 ----
    gemm_qkv<<<dim3(3*DM/128, NTOK/128), blk, 0, stream>>>(xb, WTq, bq, bk, bv, Qb);
    flash_mfma<HDIM1,2><<<dim3(SEQ/128, NH1, BATCH), blk, 0, stream>>>(
        Qb, Qb + OUTN, Qb + 2*OUTN, ob, SEQ, 0.125f);
    gemm_bt_f32<<<dim3(DM/128, NTOK/128), blk, 0, stream>>>(ob, WTo, bo, Pf, DM, DM);
    ln_residual<<<NTOK, blk, 0, stream>>>(x, Pf, ln1g, ln1b, x1);

    // ---- gate + routing ----
    hipMemsetAsync(accum, 0, 17*sizeof(float), stream);
    hipMemsetAsync(slotmap, 0xFF, NE*BATCH*CAPE*sizeof(int), stream);
    gate_kernel<<<512, blk, 0, stream>>>(x1, gW, e1i, e2i, g1f, g2f, accum);
    route_scan<<<BATCH, dim3(64), 0, stream>>>(e1i, e2i, g2f, pos1, keep1, pos2, keep2, slotmap);

    // ---- experts: 4 chunks of 2 ----
    for (int c = 0; c < 4; ++c) {
        const int ebase = c*2;
        gather_chunk<<<2*BATCH*CAPE, blk, 0, stream>>>(x1, slotmap, Einb, ebase);
        gemm_eqkv<<<dim3(DM/128, 2*BATCH*CAPE/128, 3), blk, 0, stream>>>(
            Einb, eWTq, eWTk, eWTv, eqb, ekb, evb, ebase);
        flash_mfma<HDIM2,1><<<dim3(CAPE/64, NH2, 2*BATCH), blk, 0, stream>>>(
            eqb, ekb, evb, eob, CAPE, 0.088388347648318447f);
        gemm_eout<<<dim3(DM/128, 2*BATCH*CAPE/128), blk, 0, stream>>>(
            eob, eWTo, eoutAll + (size_t)ebase*ECB, ebase);
    }

    // ---- combine + final LN + losses ----
    combine_ln<<<NTOK, blk, 0, stream>>>(x1, eoutAll, e1i, pos1, keep1, g1f,
                                         e2i, pos2, keep2, g2f, ln2g, ln2b, out);
    finalize_loss<<<1, 1, 0, stream>>>(accum, out);
}

// Round 6
// 916.971 us; speedup vs baseline: 1.2615x; 1.1197x over previous
//
#include <hip/hip_runtime.h>
#include <hip/hip_bf16.h>
#include <math.h>

#define DM    1024
#define NH1   16
#define HDIM1 64
#define NH2   8
#define HDIM2 128
#define NE    8
#define CAPE  320
#define BATCH 8
#define SEQ   1024
#define NTOK  (BATCH*SEQ)        /* 8192 */
#define OUTN  ((long)NTOK*DM)    /* 8388608 */

typedef short bf16x8 __attribute__((ext_vector_type(8)));
typedef float f32x4  __attribute__((ext_vector_type(4)));

__device__ __forceinline__ unsigned short f2bf(float f) {
    __hip_bfloat16 h = __float2bfloat16(f);
    return *reinterpret_cast<unsigned short*>(&h);
}
__device__ __forceinline__ float bf2f(unsigned short u) {
    unsigned int x = ((unsigned int)u) << 16;
    return __builtin_bit_cast(float, x);
}

__device__ __forceinline__ void async16(const void* g, void* lds) {
    __builtin_amdgcn_global_load_lds(
        (const __attribute__((address_space(1))) unsigned int*)g,
        (__attribute__((address_space(3))) unsigned int*)lds, 16, 0, 0);
}

// ---------------- shared GEMM core: 128x128 tile, BK=32, 4 waves --------
__device__ __forceinline__ void gemm_core(
    const unsigned short* __restrict__ A, const unsigned short* __restrict__ Bt,
    int m0, int n0, int K, short* ldsA, short* ldsB, f32x4 (&acc)[4][4])
{
    const int t    = threadIdx.x;
    const int lane = t & 63, w = t >> 6;
    const int wr = w >> 1, wc = w & 1;
    const int lq = lane >> 4, lm = lane & 15;
    const int srow = w*16 + (lane >> 2);
    const int skc  = (lane & 3) * 8;
    for (int kb = 0; kb < K; kb += 32) {
        #pragma unroll
        for (int p = 0; p < 2; ++p) {
            async16(A  + (size_t)(m0 + srow + p*64)*K + kb + skc,
                    &ldsA[(w*16 + p*64)*32]);
            async16(Bt + (size_t)(n0 + srow + p*64)*K + kb + skc,
                    &ldsB[(w*16 + p*64)*32]);
        }
        __syncthreads();
        bf16x8 aF[4], bF[4];
        #pragma unroll
        for (int i = 0; i < 4; ++i)
            aF[i] = *(const bf16x8*)&ldsA[(wr*64 + i*16 + lm)*32 + lq*8];
        #pragma unroll
        for (int j = 0; j < 4; ++j)
            bF[j] = *(const bf16x8*)&ldsB[(wc*64 + j*16 + lm)*32 + lq*8];
        #pragma unroll
        for (int i = 0; i < 4; ++i)
            #pragma unroll
            for (int j = 0; j < 4; ++j)
                acc[i][j] = __builtin_amdgcn_mfma_f32_16x16x32_bf16(aF[i], bF[j], acc[i][j], 0, 0, 0);
        __syncthreads();
    }
}

// ---------------- plain GEMM (fp32 out, bias) — Wo projection ------------
__global__ __launch_bounds__(256) void gemm_bt_f32(
    const unsigned short* __restrict__ A, const unsigned short* __restrict__ Bt,
    const float* __restrict__ bias, float* __restrict__ C, int N, int K)
{
    __shared__ short ldsA[128*32];
    __shared__ short ldsB[128*32];
    const int lane = threadIdx.x & 63, w = threadIdx.x >> 6;
    const int wr = w >> 1, wc = w & 1;
    const int lq = lane >> 4, lm = lane & 15;
    const int m0 = blockIdx.y * 128, n0 = blockIdx.x * 128;
    f32x4 acc[4][4];
    #pragma unroll
    for (int i = 0; i < 4; ++i)
        #pragma unroll
        for (int j = 0; j < 4; ++j) acc[i][j] = (f32x4){0.f,0.f,0.f,0.f};
    gemm_core(A, Bt, m0, n0, K, ldsA, ldsB, acc);
    #pragma unroll
    for (int j = 0; j < 4; ++j) {
        const int gcol = n0 + wc*64 + j*16 + lm;
        const float badd = bias ? bias[gcol] : 0.f;
        #pragma unroll
        for (int i = 0; i < 4; ++i) {
            const int grow = m0 + wr*64 + i*16 + lq*4;
            #pragma unroll
            for (int r = 0; r < 4; ++r)
                C[(size_t)(grow + r)*N + gcol] = acc[i][j][r] + badd;
        }
    }
}

// ---------------- fused main QKV GEMM: Bt = [WTq;WTk;WTv] ----------------
__global__ __launch_bounds__(256) void gemm_qkv(
    const unsigned short* __restrict__ A, const unsigned short* __restrict__ Bt,
    const float* __restrict__ bq, const float* __restrict__ bk, const float* __restrict__ bv,
    unsigned short* __restrict__ C)
{
    __shared__ short ldsA[128*32];
    __shared__ short ldsB[128*32];
    const int lane = threadIdx.x & 63, w = threadIdx.x >> 6;
    const int wr = w >> 1, wc = w & 1;
    const int lq = lane >> 4, lm = lane & 15;
    const int m0 = blockIdx.y * 128, n0g = blockIdx.x * 128;
    const int buf = n0g >> 10;
    const float* bias = (buf == 0) ? bq : (buf == 1) ? bk : bv;
    unsigned short* Cb = C + (size_t)buf * OUTN;
    f32x4 acc[4][4];
    #pragma unroll
    for (int i = 0; i < 4; ++i)
        #pragma unroll
        for (int j = 0; j < 4; ++j) acc[i][j] = (f32x4){0.f,0.f,0.f,0.f};
    gemm_core(A, Bt, m0, n0g, DM, ldsA, ldsB, acc);
    #pragma unroll
    for (int j = 0; j < 4; ++j) {
        const int gcol = (n0g & 1023) + wc*64 + j*16 + lm;
        const float badd = bias[gcol];
        #pragma unroll
        for (int i = 0; i < 4; ++i) {
            const int grow = m0 + wr*64 + i*16 + lq*4;
            #pragma unroll
            for (int r = 0; r < 4; ++r)
                Cb[(size_t)(grow + r)*DM + gcol] = f2bf(acc[i][j][r] + badd);
        }
    }
}

// ---------------- expert QKV GEMM with FUSED GATHER (4 experts/chunk) ----
// A rows are expert slots; per-row source = x1b[slotmap[row]*DM + k] (or a
// zeros page for empty slots). async16's GLOBAL address is per-lane, so the
// gather costs only 2 slotmap loads/thread in the prologue — Ein buffers
// and gather_chunk kernels are eliminated. grid (8, 80, 3).
__global__ __launch_bounds__(256) void gemm_eqkv_gather(
    const unsigned short* __restrict__ X1b, const int* __restrict__ slotmap,
    const unsigned short* __restrict__ zbuf,
    const unsigned short* __restrict__ eWTq, const unsigned short* __restrict__ eWTk,
    const unsigned short* __restrict__ eWTv,
    unsigned short* __restrict__ Cq, unsigned short* __restrict__ Ck,
    unsigned short* __restrict__ Cv, int ebase)
{
    __shared__ short ldsA[128*32];
    __shared__ short ldsB[128*32];
    const int lane = threadIdx.x & 63, w = threadIdx.x >> 6;
    const int wr = w >> 1, wc = w & 1;
    const int lq = lane >> 4, lm = lane & 15;
    const int z = blockIdx.z;
    const int eloc = blockIdx.y / 20;          // 2560 rows per expert / 128
    const unsigned short* Bt =
        ((z == 0) ? eWTq : (z == 1) ? eWTk : eWTv) + (size_t)(ebase + eloc) * (1024l*1024l);
    unsigned short* C = (z == 0) ? Cq : (z == 1) ? Ck : Cv;
    const int m0 = blockIdx.y * 128, n0 = blockIdx.x * 128;
    const int srow = w*16 + (lane >> 2);
    const int skc  = (lane & 3) * 8;
    const int sbase = ebase * (BATCH*CAPE);
    const int t0 = slotmap[sbase + m0 + srow];
    const int t1 = slotmap[sbase + m0 + srow + 64];
    const unsigned short* a0 = (t0 >= 0) ? X1b + (size_t)t0 * DM : zbuf;
    const unsigned short* a1 = (t1 >= 0) ? X1b + (size_t)t1 * DM : zbuf;
    f32x4 acc[4][4];
    #pragma unroll
    for (int i = 0; i < 4; ++i)
        #pragma unroll
        for (int j = 0; j < 4; ++j) acc[i][j] = (f32x4){0.f,0.f,0.f,0.f};
    for (int kb = 0; kb < DM; kb += 32) {
        async16(a0 + kb + skc, &ldsA[(w*16)*32]);
        async16(a1 + kb + skc, &ldsA[(w*16 + 64)*32]);
        async16(Bt + (size_t)(n0 + srow)*DM + kb + skc,      &ldsB[(w*16)*32]);
        async16(Bt + (size_t)(n0 + srow + 64)*DM + kb + skc, &ldsB[(w*16 + 64)*32]);
        __syncthreads();
        bf16x8 aF[4], bF[4];
        #pragma unroll
        for (int i = 0; i < 4; ++i)
            aF[i] = *(const bf16x8*)&ldsA[(wr*64 + i*16 + lm)*32 + lq*8];
        #pragma unroll
        for (int j = 0; j < 4; ++j)
            bF[j] = *(const bf16x8*)&ldsB[(wc*64 + j*16 + lm)*32 + lq*8];
        #pragma unroll
        for (int i = 0; i < 4; ++i)
            #pragma unroll
            for (int j = 0; j < 4; ++j)
                acc[i][j] = __builtin_amdgcn_mfma_f32_16x16x32_bf16(aF[i], bF[j], acc[i][j], 0, 0, 0);
        __syncthreads();
    }
    #pragma unroll
    for (int j = 0; j < 4; ++j) {
        const int gcol = n0 + wc*64 + j*16 + lm;
        #pragma unroll
        for (int i = 0; i < 4; ++i) {
            const int grow = m0 + wr*64 + i*16 + lq*4;
            #pragma unroll
            for (int r = 0; r < 4; ++r)
                C[(size_t)(grow + r)*DM + gcol] = f2bf(acc[i][j][r]);
        }
    }
}

// ---------------- grouped expert output GEMM (bf16 out, 4 experts) ------
__global__ __launch_bounds__(256) void gemm_eout(
    const unsigned short* __restrict__ A, const unsigned short* __restrict__ eWTo,
    unsigned short* __restrict__ C, int ebase)
{
    __shared__ short ldsA[128*32];
    __shared__ short ldsB[128*32];
    const int lane = threadIdx.x & 63, w = threadIdx.x >> 6;
    const int wr = w >> 1, wc = w & 1;
    const int lq = lane >> 4, lm = lane & 15;
    const int eloc = blockIdx.y / 20;
    const unsigned short* Bt = eWTo + (size_t)(ebase + eloc) * (1024l*1024l);
    const int m0 = blockIdx.y * 128, n0 = blockIdx.x * 128;
    f32x4 acc[4][4];
    #pragma unroll
    for (int i = 0; i < 4; ++i)
        #pragma unroll
        for (int j = 0; j < 4; ++j) acc[i][j] = (f32x4){0.f,0.f,0.f,0.f};
    gemm_core(A, Bt, m0, n0, DM, ldsA, ldsB, acc);
    #pragma unroll
    for (int j = 0; j < 4; ++j) {
        const int gcol = n0 + wc*64 + j*16 + lm;
        #pragma unroll
        for (int i = 0; i < 4; ++i) {
            const int grow = m0 + wr*64 + i*16 + lq*4;
            #pragma unroll
            for (int r = 0; r < 4; ++r)
                C[(size_t)(grow + r)*DM + gcol] = f2bf(acc[i][j][r]);
        }
    }
}

// ---------------- MFMA flash attention (bf16 in/out, fp32 softmax) ------
// NS=1 (NS=2 measured neutral: L2/L3 already absorbed K/V re-reads, and
// halved grid cost TLP). pP row stride 76; V-transpose swizzle
// ((k>>3)^(d>>3)^d)&7 both sides; Q staged through ks; K/V reg-prefetch.
template<int HD, int NS>
__global__ __launch_bounds__(256) void flash_mfma(
    const unsigned short* __restrict__ Q, const unsigned short* __restrict__ K,
    const unsigned short* __restrict__ V, unsigned short* __restrict__ O,
    int rows, float scale)
{
    constexpr int KT = 64;
    constexpr int PADQ = HD + 8;
    constexpr int NKT = HD / 32;
    constexpr int NDT = HD / 16;
    constexpr int CG  = HD / 8;
    constexpr int RPR = 256 / CG;
    constexpr int NP  = KT / RPR;
    constexpr int PST = 76;
    __shared__ __align__(16) unsigned short ks[KT * PADQ];
    __shared__ __align__(16) unsigned short vt[HD * KT];
    __shared__ __align__(16) unsigned short pP[4][16 * PST];
    const int t = threadIdx.x, lane = t & 63, w = t >> 6;
    const int lm = lane & 15, quad = lane >> 4;
    const int q0 = blockIdx.x * (64 * NS);
    const long base = (long)blockIdx.z * rows * DM + (long)blockIdx.y * HD;
    const int srow = t / CG, scg = t % CG;

    bf16x8 aQ[NS][NKT];
    #pragma unroll
    for (int s = 0; s < NS; ++s) {
        if (s) __syncthreads();
        #pragma unroll
        for (int r = 0; r < 64 / RPR; ++r) {
            int row = srow + r * RPR;
            *(bf16x8*)&ks[row * PADQ + scg * 8] =
                *(const bf16x8*)&Q[base + (long)(q0 + s * 64 + row) * DM + scg * 8];
        }
        __syncthreads();
        #pragma unroll
        for (int kk = 0; kk < NKT; ++kk)
            aQ[s][kk] = *(const bf16x8*)&ks[(w * 16 + lm) * PADQ + kk * 32 + quad * 8];
    }

    float m4[NS][4], l4[NS][4];
    f32x4 aco[NS][NDT];
    #pragma unroll
    for (int s = 0; s < NS; ++s) {
        #pragma unroll
        for (int r = 0; r < 4; ++r) { m4[s][r] = -1e30f; l4[s][r] = 0.f; }
        #pragma unroll
        for (int d = 0; d < NDT; ++d) aco[s][d] = (f32x4){0.f,0.f,0.f,0.f};
    }

    bf16x8 kr[NP], vr[NP];
    #pragma unroll
    for (int r = 0; r < NP; ++r) {
        int row = srow + r * RPR;
        kr[r] = *(const bf16x8*)&K[base + (long)row * DM + scg * 8];
        vr[r] = *(const bf16x8*)&V[base + (long)row * DM + scg * 8];
    }

    for (int k0 = 0; k0 < rows; k0 += KT) {
        __syncthreads();
        #pragma unroll
        for (int r = 0; r < NP; ++r) {
            int row = srow + r * RPR;
            *(bf16x8*)&ks[row * PADQ + scg * 8] = kr[r];
            #pragma unroll
            for (int u = 0; u < 8; ++u) {
                int d = scg * 8 + u;
                vt[d * KT + ((((row >> 3) ^ (d >> 3) ^ d) & 7)) * 8 + (row & 7)] = ((short*)&vr[r])[u];
            }
        }
        __syncthreads();
        if (k0 + KT < rows) {
            #pragma unroll
            for (int r = 0; r < NP; ++r) {
                int row = srow + r * RPR;
                kr[r] = *(const bf16x8*)&K[base + (long)(k0 + KT + row) * DM + scg * 8];
                vr[r] = *(const bf16x8*)&V[base + (long)(k0 + KT + row) * DM + scg * 8];
            }
        }
        #pragma unroll
        for (int s = 0; s < NS; ++s) {
            f32x4 sc[4];
            #pragma unroll
            for (int n = 0; n < 4; ++n) {
                f32x4 c = (f32x4){0.f,0.f,0.f,0.f};
                #pragma unroll
                for (int kk = 0; kk < NKT; ++kk) {
                    bf16x8 bK = *(const bf16x8*)&ks[(n * 16 + lm) * PADQ + kk * 32 + quad * 8];
                    c = __builtin_amdgcn_mfma_f32_16x16x32_bf16(aQ[s][kk], bK, c, 0, 0, 0);
                }
                #pragma unroll
                for (int r = 0; r < 4; ++r) c[r] *= scale;
                sc[n] = c;
            }
            float alpha[4];
            #pragma unroll
            for (int r = 0; r < 4; ++r) {
                float mx = fmaxf(fmaxf(sc[0][r], sc[1][r]), fmaxf(sc[2][r], sc[3][r]));
                #pragma unroll
                for (int off = 1; off < 16; off <<= 1)
                    mx = fmaxf(mx, __shfl_xor(mx, off, 64));
                float mnew = fmaxf(m4[s][r], mx);
                alpha[r] = __expf(m4[s][r] - mnew);
                m4[s][r] = mnew;
                float sum = 0.f;
                #pragma unroll
                for (int n = 0; n < 4; ++n) {
                    float p = __expf(sc[n][r] - mnew);
                    sc[n][r] = p; sum += p;
                }
                #pragma unroll
                for (int off = 1; off < 16; off <<= 1)
                    sum += __shfl_xor(sum, off, 64);
                l4[s][r] = l4[s][r] * alpha[r] + sum;
            }
            #pragma unroll
            for (int n = 0; n < 4; ++n)
                #pragma unroll
                for (int r = 0; r < 4; ++r)
                    pP[w][(quad * 4 + r) * PST + n * 16 + lm] = f2bf(sc[n][r]);
            #pragma unroll
            for (int d = 0; d < NDT; ++d)
                #pragma unroll
                for (int r = 0; r < 4; ++r) aco[s][d][r] *= alpha[r];
            #pragma unroll
            for (int d = 0; d < NDT; ++d) {
                #pragma unroll
                for (int kk = 0; kk < 2; ++kk) {
                    bf16x8 aP = *(const bf16x8*)&pP[w][lm * PST + kk * 32 + quad * 8];
                    int dd = d * 16 + lm;
                    int jb = kk * 4 + quad;
                    bf16x8 bV = *(const bf16x8*)&vt[dd * KT + (((jb ^ (dd >> 3) ^ dd) & 7) * 8)];
                    aco[s][d] = __builtin_amdgcn_mfma_f32_16x16x32_bf16(aP, bV, aco[s][d], 0, 0, 0);
                }
            }
        }
    }
    #pragma unroll
    for (int s = 0; s < NS; ++s)
        #pragma unroll
        for (int r = 0; r < 4; ++r) {
            float inv = 1.f / l4[s][r];
            #pragma unroll
            for (int d = 0; d < NDT; ++d)
                O[base + (long)(q0 + s * 64 + w * 16 + quad * 4 + r) * DM + d * 16 + lm] =
                    f2bf(aco[s][d][r] * inv);
        }
}

// ---------------- weight transpose + fp32->bf16 -------------------------
__global__ __launch_bounds__(256) void transpose_bf16(
    const float* __restrict__ src, unsigned short* __restrict__ dst)
{
    __shared__ float tile[32][33];
    const long mb = (long)blockIdx.z * (1024l*1024l);
    const int tx = threadIdx.x & 31, ty = threadIdx.x >> 5;
    const int r0 = blockIdx.y * 32, c0 = blockIdx.x * 32;
    #pragma unroll
    for (int rr = ty; rr < 32; rr += 8)
        tile[rr][tx] = src[mb + (long)(r0+rr)*1024 + c0 + tx];
    __syncthreads();
    #pragma unroll
    for (int rr = ty; rr < 32; rr += 8)
        dst[mb + (long)(c0+rr)*1024 + r0 + tx] = f2bf(tile[tx][rr]);
}

// ---------------- flat fp32 -> bf16 convert ----------------------------
__global__ __launch_bounds__(256) void convert_bf16(
    const float* __restrict__ src, unsigned short* __restrict__ dst, long n)
{
    long i = ((long)blockIdx.x*256 + threadIdx.x)*4;
    if (i >= n) return;
    float4 v = *(const float4*)&src[i];
    ushort4 o = { f2bf(v.x), f2bf(v.y), f2bf(v.z), f2bf(v.w) };
    *(ushort4*)&dst[i] = o;
}

// ---------------- Residual + LayerNorm (fp32 -> out, bf16 -> x1b) -------
__global__ __launch_bounds__(256) void ln_residual(
    const float* __restrict__ X, const float* __restrict__ R,
    const float* __restrict__ gam, const float* __restrict__ bet,
    float* __restrict__ Yf, unsigned short* __restrict__ Yb)
{
    const long row = blockIdx.x;
    const int t = threadIdx.x;
    float4 xv = *(const float4*)&X[row*DM + t*4];
    float4 rv = *(const float4*)&R[row*DM + t*4];
    float v0=xv.x+rv.x, v1=xv.y+rv.y, v2=xv.z+rv.z, v3=xv.w+rv.w;
    float s  = v0+v1+v2+v3;
    float s2 = v0*v0+v1*v1+v2*v2+v3*v3;
    #pragma unroll
    for (int off = 32; off > 0; off >>= 1) {
        s  += __shfl_down(s,  off, 64);
        s2 += __shfl_down(s2, off, 64);
    }
    __shared__ float red[8];
    __shared__ float mv[2];
    const int wid = t >> 6;
    if ((t & 63) == 0) { red[wid] = s; red[4+wid] = s2; }
    __syncthreads();
    if (t == 0) {
        float S  = red[0]+red[1]+red[2]+red[3];
        float S2 = red[4]+red[5]+red[6]+red[7];
        float mean = S * (1.f/DM);
        float var  = S2 * (1.f/DM) - mean*mean;
        mv[0] = mean; mv[1] = rsqrtf(var + 1e-5f);
    }
    __syncthreads();
    float mean = mv[0], inv = mv[1];
    float4 g4 = *(const float4*)&gam[t*4];
    float4 b4 = *(const float4*)&bet[t*4];
    float4 o4;
    o4.x = (v0-mean)*inv*g4.x + b4.x;
    o4.y = (v1-mean)*inv*g4.y + b4.y;
    o4.z = (v2-mean)*inv*g4.z + b4.z;
    o4.w = (v3-mean)*inv*g4.w + b4.w;
    *(float4*)&Yf[row*DM + t*4] = o4;
    ushort4 ub = { f2bf(o4.x), f2bf(o4.y), f2bf(o4.z), f2bf(o4.w) };
    *(ushort4*)&Yb[row*DM + t*4] = ub;
}

// ---------------- Per-chunk token accumulate: out += gated expert outs --
// Token-owned blocks -> no write races; chunks stream-ordered.
__global__ __launch_bounds__(256) void accum_chunk(
    float* __restrict__ out, const unsigned short* __restrict__ Eout,
    const int* __restrict__ e1, const int* __restrict__ pos1,
    const int* __restrict__ keep1, const float* __restrict__ g1,
    const int* __restrict__ e2, const int* __restrict__ pos2,
    const int* __restrict__ keep2, const float* __restrict__ g2,
    int ebase)
{
    const long row = blockIdx.x;
    const int b = (int)(row >> 10);
    const int t = threadIdx.x;
    const int E1 = e1[row] - ebase;
    const int E2 = e2[row] - ebase;
    const bool h1 = (E1 >= 0) && (E1 < 4) && (keep1[row] != 0);
    const bool h2 = (E2 >= 0) && (E2 < 4) && (keep2[row] != 0);
    if (!h1 && !h2) return;
    float4 acc = *(const float4*)&out[row*DM + t*4];
    if (h1) {
        const float w1 = g1[row];
        ushort4 u = *(const ushort4*)&Eout[((size_t)(E1*BATCH + b)*CAPE + pos1[row])*DM + t*4];
        acc.x += w1*bf2f(u.x); acc.y += w1*bf2f(u.y);
        acc.z += w1*bf2f(u.z); acc.w += w1*bf2f(u.w);
    }
    if (h2) {
        const float w2 = g2[row];
        ushort4 u = *(const ushort4*)&Eout[((size_t)(E2*BATCH + b)*CAPE + pos2[row])*DM + t*4];
        acc.x += w2*bf2f(u.x); acc.y += w2*bf2f(u.y);
        acc.z += w2*bf2f(u.z); acc.w += w2*bf2f(u.w);
    }
    *(float4*)&out[row*DM + t*4] = acc;
}

// ---------------- Final in-place LayerNorm (LN2) ------------------------
__global__ __launch_bounds__(256) void ln_inplace(
    float* __restrict__ Y, const float* __restrict__ gam, const float* __restrict__ bet)
{
    const long row = blockIdx.x;
    const int t = threadIdx.x;
    float4 xv = *(const float4*)&Y[row*DM + t*4];
    float v0=xv.x, v1=xv.y, v2=xv.z, v3=xv.w;
    float s  = v0+v1+v2+v3;
    float s2 = v0*v0+v1*v1+v2*v2+v3*v3;
    #pragma unroll
    for (int off = 32; off > 0; off >>= 1) {
        s  += __shfl_down(s,  off, 64);
        s2 += __shfl_down(s2, off, 64);
    }
    __shared__ float red[8];
    __shared__ float mv[2];
    const int wid = t >> 6;
    if ((t & 63) == 0) { red[wid] = s; red[4+wid] = s2; }
    __syncthreads();
    if (t == 0) {
        float S  = red[0]+red[1]+red[2]+red[3];
        float S2 = red[4]+red[5]+red[6]+red[7];
        float mean = S * (1.f/DM);
        float var  = S2 * (1.f/DM) - mean*mean;
        mv[0] = mean; mv[1] = rsqrtf(var + 1e-5f);
    }
    __syncthreads();
    float mean = mv[0], inv = mv[1];
    float4 g4 = *(const float4*)&gam[t*4];
    float4 b4 = *(const float4*)&bet[t*4];
    float4 o4;
    o4.x = (v0-mean)*inv*g4.x + b4.x;
    o4.y = (v1-mean)*inv*g4.y + b4.y;
    o4.z = (v2-mean)*inv*g4.z + b4.z;
    o4.w = (v3-mean)*inv*g4.w + b4.w;
    *(float4*)&Y[row*DM + t*4] = o4;
}

// ---------------- Gate: 512 blocks x 4 waves, 1 wave per token ----------
__global__ __launch_bounds__(256) void gate_kernel(
    const float* __restrict__ X1, const float* __restrict__ gW,
    int* __restrict__ e1, int* __restrict__ e2,
    float* __restrict__ g1, float* __restrict__ g2,
    float* __restrict__ accum)
{
    const int t = threadIdx.x, l = t & 63, w = t >> 6;
    const int gwave = blockIdx.x * 4 + w;     // 0..2047
    float zacc = 0.f, pacc[8], facc[8];
    #pragma unroll
    for (int e = 0; e < 8; ++e) { pacc[e] = 0.f; facc[e] = 0.f; }

    for (int tok = gwave; tok < NTOK; tok += 2048) {
        const float* xr = X1 + (long)tok*DM;
        float part[8];
        #pragma unroll
        for (int e = 0; e < 8; ++e) part[e] = 0.f;
        #pragma unroll
        for (int pass = 0; pass < 4; ++pass) {
            const int i0 = pass*256 + l*4;
            float4 xv = *(const float4*)&xr[i0];
            const float xs[4] = {xv.x, xv.y, xv.z, xv.w};
            #pragma unroll
            for (int u = 0; u < 4; ++u) {
                float4 w0 = *(const float4*)&gW[(i0+u)*8];
                float4 w1 = *(const float4*)&gW[(i0+u)*8+4];
                part[0]+=xs[u]*w0.x; part[1]+=xs[u]*w0.y; part[2]+=xs[u]*w0.z; part[3]+=xs[u]*w0.w;
                part[4]+=xs[u]*w1.x; part[5]+=xs[u]*w1.y; part[6]+=xs[u]*w1.z; part[7]+=xs[u]*w1.w;
            }
        }
        #pragma unroll
        for (int e = 0; e < 8; ++e) {
            float v = part[e];
            #pragma unroll
            for (int off = 32; off > 0; off >>= 1) v += __shfl_down(v, off, 64);
            part[e] = v;
        }
        if (l == 0) {
            float mx = part[0];
            #pragma unroll
            for (int e = 1; e < 8; ++e) mx = fmaxf(mx, part[e]);
            float p[8]; float sum = 0.f;
            #pragma unroll
            for (int e = 0; e < 8; ++e) { p[e] = __expf(part[e]-mx); sum += p[e]; }
            float lse = mx + __logf(sum);
            float isum = 1.f/sum;
            #pragma unroll
            for (int e = 0; e < 8; ++e) { p[e] *= isum; pacc[e] += p[e]; }
            int b1 = 0;
            #pragma unroll
            for (int e = 1; e < 8; ++e) if (p[e] > p[b1]) b1 = e;
            int b2 = (b1 == 0) ? 1 : 0;
            #pragma unroll
            for (int e = 0; e < 8; ++e) if (e != b1 && e != b2 && p[e] > p[b2]) b2 = e;
            e1[tok] = b1; e2[tok] = b2; g1[tok] = p[b1]; g2[tok] = p[b2];
            zacc += lse*lse;
            facc[b1] += 1.f;
        }
    }
    __shared__ float red[4][17];
    if (l == 0) {
        red[w][0] = zacc;
        #pragma unroll
        for (int e = 0; e < 8; ++e) { red[w][1+e] = pacc[e]; red[w][9+e] = facc[e]; }
    }
    __syncthreads();
    if (t < 17)
        atomicAdd(&accum[t], red[0][t] + red[1][t] + red[2][t] + red[3][t]);
}

// ---------------- Routing scan ------------------------------------------
__global__ __launch_bounds__(64) void route_scan(
    const int* __restrict__ e1, const int* __restrict__ e2,
    const float* __restrict__ g2,
    int* __restrict__ pos1, int* __restrict__ keep1,
    int* __restrict__ pos2, int* __restrict__ keep2,
    int* __restrict__ slotmap)
{
    const int b = blockIdx.x;
    const int l = threadIdx.x;
    __shared__ int cnt[8];
    if (l < 8) cnt[l] = 0;
    __syncthreads();
    for (int slot = 0; slot < 2; ++slot) {
        const int* eArr = slot ? e2 : e1;
        for (int c = 0; c < SEQ/64; ++c) {
            const int tk = b*SEQ + c*64 + l;
            const int e = eArr[tk];
            const bool valid = slot ? (g2[tk] > 0.2f) : true;
            unsigned long long mymask = 0ull; int addmine = 0;
            #pragma unroll
            for (int ee = 0; ee < 8; ++ee) {
                unsigned long long bm = __ballot(valid && (e == ee));
                if (e == ee) mymask = bm;
                if (l == ee) addmine = (int)__popcll(bm);
            }
            const int p  = cnt[e] + (int)__popcll(mymask & ((1ull << l) - 1ull));
            const int kp = (valid && p < CAPE) ? 1 : 0;
            const int pc = p < CAPE ? p : (CAPE-1);
            if (slot == 0) { pos1[tk] = pc; keep1[tk] = kp; }
            else           { pos2[tk] = pc; keep2[tk] = kp; }
            if (kp) slotmap[(e*BATCH + b)*CAPE + pc] = tk;
            __syncthreads();
            if (l < 8) cnt[l] += addmine;
            __syncthreads();
        }
    }
}

// ---------------- Loss scalars ------------------------------------------
__global__ void finalize_loss(const float* __restrict__ accum, float* __restrict__ out)
{
    float z = accum[0] * (1.0f/NTOK);
    float s = 0.f;
    for (int e = 0; e < 8; ++e)
        s += (accum[1+e] * (1.0f/NTOK)) * (accum[9+e] * (1.0f/NTOK));
    float bal = 0.01f * 8.0f * s;
    float zl  = 0.001f * z;
    out[OUTN]   = bal + zl;
    out[OUTN+1] = bal;
    out[OUTN+2] = zl;
}

extern "C" void kernel_launch(void* const* d_in, const int* in_sizes, int n_in,
                              void* d_out, int out_size, void* d_ws, size_t ws_size,
                              hipStream_t stream)
{
    (void)in_sizes; (void)n_in; (void)out_size; (void)ws_size;
    const float* x    = (const float*)d_in[0];
    const float* Wq   = (const float*)d_in[1];
    const float* Wk   = (const float*)d_in[2];
    const float* Wv   = (const float*)d_in[3];
    const float* Wo   = (const float*)d_in[4];
    const float* bq   = (const float*)d_in[5];
    const float* bk   = (const float*)d_in[6];
    const float* bv   = (const float*)d_in[7];
    const float* bo   = (const float*)d_in[8];
    const float* ln1g = (const float*)d_in[9];
    const float* ln1b = (const float*)d_in[10];
    const float* ln2g = (const float*)d_in[11];
    const float* ln2b = (const float*)d_in[12];
    const float* gW   = (const float*)d_in[13];
    const float* eWq  = (const float*)d_in[14];
    const float* eWk  = (const float*)d_in[15];
    const float* eWv  = (const float*)d_in[16];
    const float* eWo  = (const float*)d_in[17];
    float* out = (float*)d_out;

    char* ws = (char*)d_ws;
    const size_t MB = 1048576;
    const long MATE = 1024l*1024l;
    // ---- layout (peak 170 MB; x1 fp32 lives in d_out) ----
    // 0-72: bf16 transposed weights
    unsigned short* WTq  = (unsigned short*)(ws);
    unsigned short* WTk  = WTq + 1*MATE;
    unsigned short* WTv  = WTq + 2*MATE;
    unsigned short* WTo  = WTq + 3*MATE;
    unsigned short* eWTq = WTq + 4*MATE;
    unsigned short* eWTk = WTq + 12*MATE;
    unsigned short* eWTv = WTq + 20*MATE;
    unsigned short* eWTo = WTq + 28*MATE;
    // 72-73: routing/meta
    int*   e1i   = (int*)(ws + 72*MB);
    int*   e2i   = e1i + NTOK;
    int*   pos1  = e1i + 2*NTOK;
    int*   pos2  = e1i + 3*NTOK;
    int*   keep1 = e1i + 4*NTOK;
    int*   keep2 = e1i + 5*NTOK;
    int*   slotmap = e1i + 6*NTOK;                          // 20480 ints
    float* g1f   = (float*)(e1i + 6*NTOK + NE*BATCH*CAPE);
    float* g2f   = g1f + NTOK;
    float* accum = g2f + NTOK;                              // 17 floats
    // 73: zeros page (4 KB) for empty expert slots
    unsigned short* zbuf = (unsigned short*)(ws + 73*MB);
    // stage-1: xb 74-90 (x1b reuses after), ob 90-106, Qb 106-154 (Pf alias)
    unsigned short* xb  = (unsigned short*)(ws + 74*MB);
    unsigned short* x1b = (unsigned short*)(ws + 74*MB);    // bf16 x1 (after xb dead)
    unsigned short* ob  = (unsigned short*)(ws + 90*MB);
    unsigned short* Qb  = (unsigned short*)(ws + 106*MB);   // Q/K/V contiguous 48 MB
    float* Pf = (float*)(ws + 106*MB);                      // fp32 Wo out (alias Q/K)
    // expert phase (4 experts/chunk): q/k/v/eob 20 MB each, 90-170
    unsigned short* eqb = (unsigned short*)(ws + 90*MB);    // also eout alias after flash
    unsigned short* ekb = (unsigned short*)(ws + 110*MB);
    unsigned short* evb = (unsigned short*)(ws + 130*MB);
    unsigned short* eob = (unsigned short*)(ws + 150*MB);
    unsigned short* eoc = eqb;                              // eout GEMM result (q dead)

    dim3 blk(256);
    dim3 tgrid(32, 32, 1), tgrid8(32, 32, 8);

    // ---- weight prep ----
    transpose_bf16<<<tgrid,  blk, 0, stream>>>(Wq,  WTq);
    transpose_bf16<<<tgrid,  blk, 0, stream>>>(Wk,  WTk);
    transpose_bf16<<<tgrid,  blk, 0, stream>>>(Wv,  WTv);
    transpose_bf16<<<tgrid,  blk, 0, stream>>>(Wo,  WTo);
    transpose_bf16<<<tgrid8, blk, 0, stream>>>(eWq, eWTq);
    transpose_bf16<<<tgrid8, blk, 0, stream>>>(eWk, eWTk);
    transpose_bf16<<<tgrid8, blk, 0, stream>>>(eWv, eWTv);
    transpose_bf16<<<tgrid8, blk, 0, stream>>>(eWo, eWTo);
    convert_bf16<<<NTOK, blk, 0, stream>>>(x, xb, OUTN);

    // ---- stage 1: MHA + LN1 (x1 -> out fp32 + x1b bf16) ----
    gemm_qkv<<<dim3(3*DM/128, NTOK/128), blk, 0, stream>>>(xb, WTq, bq, bk, bv, Qb);
    flash_mfma<HDIM1,1><<<dim3(SEQ/64, NH1, BATCH), blk, 0, stream>>>(
        Qb, Qb + OUTN, Qb + 2*OUTN, ob, SEQ, 0.125f);
    gemm_bt_f32<<<dim3(DM/128, NTOK/128), blk, 0, stream>>>(ob, WTo, bo, Pf, DM, DM);
    ln_residual<<<NTOK, blk, 0, stream>>>(x, Pf, ln1g, ln1b, out, x1b);

    // ---- gate + routing ----
    hipMemsetAsync(accum, 0, 17*sizeof(float), stream);
    hipMemsetAsync(slotmap, 0xFF, NE*BATCH*CAPE*sizeof(int), stream);
    hipMemsetAsync(zbuf, 0, 4096, stream);
    gate_kernel<<<512, blk, 0, stream>>>(out, gW, e1i, e2i, g1f, g2f, accum);
    route_scan<<<BATCH, dim3(64), 0, stream>>>(e1i, e2i, g2f, pos1, keep1, pos2, keep2, slotmap);

    // ---- experts: 2 chunks of 4 ----
    for (int c = 0; c < 2; ++c) {
        const int ebase = c*4;
        gemm_eqkv_gather<<<dim3(DM/128, 4*BATCH*CAPE/128, 3), blk, 0, stream>>>(
            x1b, slotmap, zbuf, eWTq, eWTk, eWTv, eqb, ekb, evb, ebase);
        flash_mfma<HDIM2,1><<<dim3(CAPE/64, NH2, 4*BATCH), blk, 0, stream>>>(
            eqb, ekb, evb, eob, CAPE, 0.088388347648318447f);
        gemm_eout<<<dim3(DM/128, 4*BATCH*CAPE/128), blk, 0, stream>>>(
            eob, eWTo, eoc, ebase);
        accum_chunk<<<NTOK, blk, 0, stream>>>(out, eoc, e1i, pos1, keep1, g1f,
                                              e2i, pos2, keep2, g2f, ebase);
    }

    // ---- final LN + losses ----
    ln_inplace<<<NTOK, blk, 0, stream>>>(out, ln2g, ln2b);
    finalize_loss<<<1, 1, 0, stream>>>(accum, out);
}